// Round 3
// baseline (833.386 us; speedup 1.0000x reference)
//
#include <hip/hip_runtime.h>
#include <hip/hip_bf16.h>
#include <hip/hip_cooperative_groups.h>

namespace cg = cooperative_groups;

// HybridBridge round 9: collapse prep/ctx_a..d/statsattn(h=0) into ONE
// cooperative kernel (grid.sync between phases) — dispatch count 11 -> 7.
// GEMMs unchanged (256x256 8-phase counted-vmcnt schedule).
// B=8, L=4096, D=512, C=256, T=2, H=2, HD=256. N = 32768 rows.

#define N_TOK 32768
#define HALF_ROWS 16384

typedef unsigned short u16;
typedef __attribute__((ext_vector_type(8))) __bf16 bf16x8;
typedef __attribute__((ext_vector_type(4))) float f32x4;

__device__ __forceinline__ float bf2f(unsigned int h) { return __uint_as_float(h << 16); }
__device__ __forceinline__ u16 f2bf(float f) {
    unsigned int u = __float_as_uint(f);
    u += 0x7FFFu + ((u >> 16) & 1u);   // RNE
    return (u16)(u >> 16);
}
__device__ __forceinline__ void load8(const u16* p, float* v) {
    uint4 u = *(const uint4*)p;
    v[0] = bf2f(u.x & 0xffffu); v[1] = bf2f(u.x >> 16);
    v[2] = bf2f(u.y & 0xffffu); v[3] = bf2f(u.y >> 16);
    v[4] = bf2f(u.z & 0xffffu); v[5] = bf2f(u.z >> 16);
    v[6] = bf2f(u.w & 0xffffu); v[7] = bf2f(u.w >> 16);
}
__device__ __forceinline__ uint4 pack8(const float* v) {
    uint4 u;
    u.x = (unsigned)f2bf(v[0]) | ((unsigned)f2bf(v[1]) << 16);
    u.y = (unsigned)f2bf(v[2]) | ((unsigned)f2bf(v[3]) << 16);
    u.z = (unsigned)f2bf(v[4]) | ((unsigned)f2bf(v[5]) << 16);
    u.w = (unsigned)f2bf(v[6]) | ((unsigned)f2bf(v[7]) << 16);
    return u;
}
__device__ __forceinline__ void async16(const u16* g, u16* lds) {
    __builtin_amdgcn_global_load_lds(
        (const __attribute__((address_space(1))) unsigned int*)g,
        (__attribute__((address_space(3))) unsigned int*)lds, 16, 0, 0);
}

#define FENCE() asm volatile("" ::: "memory")
#define BARRIER() do { FENCE(); __builtin_amdgcn_s_barrier(); FENCE(); } while (0)
#define WAITV(n) asm volatile("s_waitcnt vmcnt(" #n ")" ::: "memory")
#define LGKM0()  asm volatile("s_waitcnt lgkmcnt(0)" ::: "memory")

// ==== phase bodies (verbatim ports of the old standalone kernels) ========

__device__ void prep_body(unsigned bid, int tid,
                          const float* __restrict__ in_proj_w,
                          const float* __restrict__ in_proj_b,
                          const float* __restrict__ qb,
                          const float* __restrict__ concat_w,
                          const float* __restrict__ mix_w1,
                          const float* __restrict__ mix_w2,
                          const float* __restrict__ context,
                          float* __restrict__ bqp,
                          u16* __restrict__ cwbf, u16* __restrict__ m1bf,
                          u16* __restrict__ m2bf, u16* __restrict__ ctxbf) {
    if (bid < 128) {
        const int wave = tid >> 6, lane = tid & 63;
        const int j = bid * 4 + wave;
        const int i = lane * 8;
        float4 w0 = *(const float4*)(in_proj_w + (size_t)j * 512 + i);
        float4 w1 = *(const float4*)(in_proj_w + (size_t)j * 512 + i + 4);
        float4 b0 = *(const float4*)(qb + i);
        float4 b1 = *(const float4*)(qb + i + 4);
        float p1 = w0.x*b0.x + w0.y*b0.y + w0.z*b0.z + w0.w*b0.w
                 + w1.x*b1.x + w1.y*b1.y + w1.z*b1.z + w1.w*b1.w;
        for (int m = 1; m < 64; m <<= 1) p1 += __shfl_xor(p1, m, 64);
        if (lane == 0) bqp[j] = in_proj_b[j] + p1;
    } else if (bid < 320) {
        int i = (bid - 128) * 256 + tid;           // < 49152
        const float* s = concat_w + (size_t)i * 8;
        float4 a = *(const float4*)s;
        float4 b = *(const float4*)(s + 4);
        float v[8] = {a.x, a.y, a.z, a.w, b.x, b.y, b.z, b.w};
        *(uint4*)(cwbf + (size_t)i * 8) = pack8(v);
    } else if (bid < 576) {
        int i = (bid - 320) * 256 + tid;           // < 65536
        const float* s = mix_w2 + (size_t)i * 8;
        float4 a = *(const float4*)s;
        float4 b = *(const float4*)(s + 4);
        float v[8] = {a.x, a.y, a.z, a.w, b.x, b.y, b.z, b.w};
        *(uint4*)(m2bf + (size_t)i * 8) = pack8(v);
    } else if (bid < 1344) {
        int idx = (bid - 576) * 256 + tid;         // < 196608
        int n = idx / 192;
        int k = (idx - n * 192) * 8;
        const float* base = mix_w1 + (size_t)n * 2048;
        float v[8];
        if (k < 512) {
            #pragma unroll
            for (int e = 0; e < 8; e++) v[e] = base[k + e] + base[1024 + k + e];
        } else if (k < 1024) {
            #pragma unroll
            for (int e = 0; e < 8; e++) v[e] = base[k + e] - base[512 + k + e];
        } else {
            #pragma unroll
            for (int e = 0; e < 8; e++) v[e] = base[512 + k + e];
        }
        *(uint4*)(m1bf + (size_t)n * 1536 + k) = pack8(v);
    } else {
        for (int i = tid; i < 2048; i += 256)
            ctxbf[i] = f2bf(context[i]);
    }
}

__device__ void ctx_a_body(unsigned task, int tid,
                           const float* __restrict__ context,
                           const float* __restrict__ film_w, const float* __restrict__ film_b,
                           const float* __restrict__ gate_w, const float* __restrict__ gate_b,
                           const float* __restrict__ ctx_w1, const float* __restrict__ ctx_b1,
                           float* __restrict__ gb1, float* __restrict__ betab,
                           float* __restrict__ gateb, float* __restrict__ hbuf) {
    const int wave = tid >> 6, lane = tid & 63;
    const int widx = (int)task * 4 + wave;        // 0..16383
    const int b   = widx >> 11;
    const int j2  = widx & 2047;
    const int cat = j2 >> 9;
    const int j   = j2 & 511;
    const float* wrow;
    if      (cat == 0) wrow = film_w + (size_t)j * 256;
    else if (cat == 1) wrow = film_w + (size_t)(512 + j) * 256;
    else if (cat == 2) wrow = gate_w + (size_t)j * 256;
    else               wrow = ctx_w1 + (size_t)j * 256;
    float4 wv = *(const float4*)(wrow + lane * 4);
    float4 cv = *(const float4*)(context + b * 256 + lane * 4);
    float s = wv.x * cv.x + wv.y * cv.y + wv.z * cv.z + wv.w * cv.w;
    for (int m = 1; m < 64; m <<= 1) s += __shfl_xor(s, m, 64);
    if (lane == 0) {
        if      (cat == 0) gb1[b * 512 + j]   = 1.0f + s + film_b[j];
        else if (cat == 1) betab[b * 512 + j] = s + film_b[512 + j];
        else if (cat == 2) gateb[b * 512 + j] = 1.f / (1.f + expf(-(s + gate_b[j])));
        else {
            float hv = s + ctx_b1[j];
            hbuf[b * 512 + j] = 0.5f * hv * (1.0f + erff(hv * 0.70710678118654752f));
        }
    }
}

__device__ void ctx_b_body(unsigned task, int tid,
                           const float* __restrict__ hbuf,
                           const float* __restrict__ ctx_w2, const float* __restrict__ ctx_b2,
                           float* __restrict__ tokbuf) {
    const int wave = tid >> 6, lane = tid & 63;
    const int widx = (int)task * 4 + wave;        // 0..8191
    const int b = widx >> 10;
    const int j = widx & 1023;
    const float* wrow = ctx_w2 + (size_t)j * 512 + lane * 8;
    const float* hr   = hbuf + b * 512 + lane * 8;
    float4 w0 = *(const float4*)wrow, w1 = *(const float4*)(wrow + 4);
    float4 h0 = *(const float4*)hr,   h1 = *(const float4*)(hr + 4);
    float s = w0.x*h0.x + w0.y*h0.y + w0.z*h0.z + w0.w*h0.w
            + w1.x*h1.x + w1.y*h1.y + w1.z*h1.z + w1.w*h1.w;
    for (int m = 1; m < 64; m <<= 1) s += __shfl_xor(s, m, 64);
    if (lane == 0) tokbuf[b * 1024 + j] = s + ctx_b2[j];
}

__device__ void ctx_c_body(unsigned task, int tid,
                           const float* __restrict__ tokbuf,
                           const float* __restrict__ in_proj_w, const float* __restrict__ in_proj_b,
                           float* __restrict__ kbuf, float* __restrict__ vbuf) {
    const int wave = tid >> 6, lane = tid & 63;
    const int widx = (int)task * 4 + wave;        // 0..16383
    const int b  = widx >> 11;
    const int r  = widx & 2047;
    const int t  = r >> 10;
    const int kv = (r >> 9) & 1;
    const int j  = r & 511;
    const float* wrow = in_proj_w + (size_t)(512 + kv * 512 + j) * 512 + lane * 8;
    const float* tk   = tokbuf + (b * 2 + t) * 512 + lane * 8;
    float4 w0 = *(const float4*)wrow, w1 = *(const float4*)(wrow + 4);
    float4 t0 = *(const float4*)tk,   t1 = *(const float4*)(tk + 4);
    float s = w0.x*t0.x + w0.y*t0.y + w0.z*t0.z + w0.w*t0.w
            + w1.x*t1.x + w1.y*t1.y + w1.z*t1.z + w1.w*t1.w;
    for (int m = 1; m < 64; m <<= 1) s += __shfl_xor(s, m, 64);
    if (lane == 0) {
        float v = s + in_proj_b[512 + kv * 512 + j];
        if (kv == 0) kbuf[(b * 2 + t) * 512 + j] = v;
        else         vbuf[(b * 2 + t) * 512 + j] = v;
    }
}

__device__ void ctx_d_body(unsigned task, int tid, float* sh, float* red,
                           const float* __restrict__ in_proj_w,
                           const float* __restrict__ out_proj_w,
                           const float* __restrict__ qg, const float* __restrict__ bqp,
                           const float* __restrict__ kbuf, const float* __restrict__ vbuf,
                           float* __restrict__ ubuf, float* __restrict__ vobuf,
                           float* __restrict__ subuf, float* __restrict__ c0buf) {
    if (task < 32) {
        const int bid = (int)task;
        const int b = bid >> 2, idx = bid & 3;
        const int t = idx >> 1, h = idx & 1;
        sh[tid] = kbuf[(b * 2 + t) * 512 + h * 256 + tid];
        __syncthreads();
        float a0 = 0.f, a1 = 0.f;
        #pragma unroll 4
        for (int dd = 0; dd < 256; dd++) {
            const float kv = sh[dd];
            const float* wr = in_proj_w + (size_t)(h * 256 + dd) * 512;
            a0 += kv * wr[tid];
            a1 += kv * wr[tid + 256];
        }
        float u0 = a0 * qg[tid], u1 = a1 * qg[tid + 256];
        ubuf[bid * 512 + tid]       = u0;
        ubuf[bid * 512 + tid + 256] = u1;
        red[tid] = u0 + u1;
        __syncthreads();
        for (int s = 128; s > 0; s >>= 1) { if (tid < s) red[tid] += red[tid + s]; __syncthreads(); }
        if (tid == 0) subuf[bid] = red[0];
        __syncthreads();
        red[tid] = bqp[h * 256 + tid] * sh[tid];
        __syncthreads();
        for (int s = 128; s > 0; s >>= 1) { if (tid < s) red[tid] += red[tid + s]; __syncthreads(); }
        if (tid == 0) c0buf[bid] = red[0];
    } else {
        const int bid = (int)task - 32;
        const int b = bid >> 2, idx = bid & 3;
        const int t = idx >> 1, h = idx & 1;
        sh[tid] = vbuf[(b * 2 + t) * 512 + h * 256 + tid];
        __syncthreads();
        const float* w0 = out_proj_w + (size_t)tid * 512 + h * 256;
        const float* w1 = out_proj_w + (size_t)(tid + 256) * 512 + h * 256;
        float acc0 = 0.f, acc1 = 0.f;
        #pragma unroll 2
        for (int dd = 0; dd < 256; dd += 4) {
            float4 x0 = *(const float4*)(w0 + dd);
            float4 x1 = *(const float4*)(w1 + dd);
            acc0 += x0.x*sh[dd] + x0.y*sh[dd+1] + x0.z*sh[dd+2] + x0.w*sh[dd+3];
            acc1 += x1.x*sh[dd] + x1.y*sh[dd+1] + x1.z*sh[dd+2] + x1.w*sh[dd+3];
        }
        vobuf[bid * 512 + tid]       = acc0;
        vobuf[bid * 512 + tid + 256] = acc1;
        __syncthreads();
    }
}

// fused stats + attn, 2 rows per wave: xbf->mixA[:,0:512], ao->mixA[:,512:1024],
// x*ao->pbufH (local rows)
__device__ void statsattn_body(unsigned task, int tid, int rowbase,
                               const float* __restrict__ x, float* __restrict__ stats,
                               u16* __restrict__ mixA, u16* __restrict__ pbufH,
                               const float* __restrict__ ubuf, const float* __restrict__ subuf,
                               const float* __restrict__ c0buf, const float* __restrict__ vobuf,
                               const float* __restrict__ ob) {
    const int wave = tid >> 6, lane = tid & 63;
    const size_t lr = (size_t)task * 8 + wave * 2;   // local rows lr, lr+1
    const size_t gr = lr + rowbase;
    const int b = (int)(gr >> 12);                   // same for both rows
    float v[2][8], s[2] = {0.f, 0.f}, ss[2] = {0.f, 0.f};
    #pragma unroll
    for (int r = 0; r < 2; r++) {
        const float* xr = x + (gr + r) * 512 + lane * 8;
        float4 a = *(const float4*)xr;
        float4 c = *(const float4*)(xr + 4);
        v[r][0]=a.x; v[r][1]=a.y; v[r][2]=a.z; v[r][3]=a.w;
        v[r][4]=c.x; v[r][5]=c.y; v[r][6]=c.z; v[r][7]=c.w;
        #pragma unroll
        for (int e = 0; e < 8; e++) { s[r] += v[r][e]; ss[r] += v[r][e] * v[r][e]; }
    }
    float u[4][8];
    #pragma unroll
    for (int idx = 0; idx < 4; idx++) {
        const float* up = ubuf + (b * 4 + idx) * 512 + lane * 8;
        float4 u0 = *(const float4*)up, u1 = *(const float4*)(up + 4);
        u[idx][0]=u0.x; u[idx][1]=u0.y; u[idx][2]=u0.z; u[idx][3]=u0.w;
        u[idx][4]=u1.x; u[idx][5]=u1.y; u[idx][6]=u1.z; u[idx][7]=u1.w;
    }
    float sd[2][4];
    #pragma unroll
    for (int r = 0; r < 2; r++)
        #pragma unroll
        for (int idx = 0; idx < 4; idx++) {
            float acc = 0.f;
            #pragma unroll
            for (int e = 0; e < 8; e++) acc += v[r][e] * u[idx][e];
            sd[r][idx] = acc;
        }
    for (int m = 1; m < 64; m <<= 1) {
        #pragma unroll
        for (int r = 0; r < 2; r++) {
            s[r] += __shfl_xor(s[r], m, 64); ss[r] += __shfl_xor(ss[r], m, 64);
            #pragma unroll
            for (int idx = 0; idx < 4; idx++) sd[r][idx] += __shfl_xor(sd[r][idx], m, 64);
        }
    }
    float vo[4][8];
    #pragma unroll
    for (int idx = 0; idx < 4; idx++) {
        const float* vp = vobuf + (b * 4 + idx) * 512 + lane * 8;
        float4 v0 = *(const float4*)vp, v1 = *(const float4*)(vp + 4);
        vo[idx][0]=v0.x; vo[idx][1]=v0.y; vo[idx][2]=v0.z; vo[idx][3]=v0.w;
        vo[idx][4]=v1.x; vo[idx][5]=v1.y; vo[idx][6]=v1.z; vo[idx][7]=v1.w;
    }
    float obp[8];
    {
        const float* op = ob + lane * 8;
        float4 o0 = *(const float4*)op, o1 = *(const float4*)(op + 4);
        obp[0]=o0.x; obp[1]=o0.y; obp[2]=o0.z; obp[3]=o0.w;
        obp[4]=o1.x; obp[5]=o1.y; obp[6]=o1.z; obp[7]=o1.w;
    }
    #pragma unroll
    for (int r = 0; r < 2; r++) {
        const float mean = s[r] * (1.f / 512.f);
        const float rstd = rsqrtf(ss[r] * (1.f / 512.f) - mean * mean + 1e-5f);
        if (lane == 0) { stats[(gr + r) * 2] = mean; stats[(gr + r) * 2 + 1] = rstd; }
        float sc[4];
        #pragma unroll
        for (int idx = 0; idx < 4; idx++)
            sc[idx] = (rstd * (sd[r][idx] - mean * subuf[b * 4 + idx]) + c0buf[b * 4 + idx]) * (1.f / 16.f);
        float p[4];
        #pragma unroll
        for (int h = 0; h < 2; h++) {
            float s0 = sc[h], s1 = sc[2 + h];
            float mx = fmaxf(s0, s1);
            float e0 = expf(s0 - mx), e1 = expf(s1 - mx);
            float inv = 1.f / (e0 + e1);
            p[h] = e0 * inv; p[2 + h] = e1 * inv;
        }
        float o[8], pr[8];
        #pragma unroll
        for (int e = 0; e < 8; e++) {
            o[e] = p[0]*vo[0][e] + p[1]*vo[1][e] + p[2]*vo[2][e] + p[3]*vo[3][e] + obp[e];
            pr[e] = v[r][e] * o[e];
        }
        *(uint4*)(mixA + (gr + r) * 1024 + lane * 8)       = pack8(v[r]);
        *(uint4*)(mixA + (gr + r) * 1024 + 512 + lane * 8) = pack8(o);
        *(uint4*)(pbufH + (lr + r) * 512 + lane * 8)       = pack8(pr);
    }
}

// ==== cooperative fused front-end: prep+ctx_a | ctx_b | ctx_c | ctx_d | sa(h=0)
__launch_bounds__(256, 2)
__global__ void ctx_fused(const float* in_proj_w, const float* in_proj_b, const float* qb,
                          const float* concat_w, const float* mix_w1, const float* mix_w2,
                          const float* context,
                          float* bqp, u16* cwbf, u16* m1bf, u16* m2bf, u16* ctxbf,
                          const float* film_w, const float* film_b,
                          const float* gate_w, const float* gate_b,
                          const float* ctx_w1, const float* ctx_b1,
                          float* gb1, float* betab, float* gateb, float* hbuf,
                          const float* ctx_w2, const float* ctx_b2, float* tokbuf,
                          float* kbuf, float* vbuf,
                          const float* out_proj_w, const float* qg,
                          float* ubuf, float* vobuf, float* subuf, float* c0buf,
                          const float* x, float* stats, u16* mixA, u16* pbufH,
                          const float* ob) {
    cg::grid_group grid = cg::this_grid();
    const int tid = threadIdx.x;
    __shared__ float sh[256];
    __shared__ float red[256];

    // P0: prep (1345 tasks) + ctx_a (4096 tasks) — independent
    for (unsigned t = blockIdx.x; t < 5441u; t += gridDim.x) {
        if (t < 1345u)
            prep_body(t, tid, in_proj_w, in_proj_b, qb, concat_w, mix_w1, mix_w2,
                      context, bqp, cwbf, m1bf, m2bf, ctxbf);
        else
            ctx_a_body(t - 1345u, tid, context, film_w, film_b, gate_w, gate_b,
                       ctx_w1, ctx_b1, gb1, betab, gateb, hbuf);
    }
    __threadfence(); grid.sync();
    // P1: ctx_b (2048 tasks)
    for (unsigned t = blockIdx.x; t < 2048u; t += gridDim.x)
        ctx_b_body(t, tid, hbuf, ctx_w2, ctx_b2, tokbuf);
    __threadfence(); grid.sync();
    // P2: ctx_c (4096 tasks)
    for (unsigned t = blockIdx.x; t < 4096u; t += gridDim.x)
        ctx_c_body(t, tid, tokbuf, in_proj_w, in_proj_b, kbuf, vbuf);
    __threadfence(); grid.sync();
    // P3: ctx_d (64 tasks)
    for (unsigned t = blockIdx.x; t < 64u; t += gridDim.x)
        ctx_d_body(t, tid, sh, red, in_proj_w, out_proj_w, qg, bqp,
                   kbuf, vbuf, ubuf, vobuf, subuf, c0buf);
    __threadfence(); grid.sync();
    // P4: statsattn h=0 (2048 tasks)
    for (unsigned t = blockIdx.x; t < 2048u; t += gridDim.x)
        statsattn_body(t, tid, 0, x, stats, mixA, pbufH,
                       ubuf, subuf, c0buf, vobuf, ob);
}

// standalone statsattn for h=1
__global__ void statsattn_kernel(const float* __restrict__ x, float* __restrict__ stats,
                                 u16* __restrict__ mixA, u16* __restrict__ pbufH,
                                 const float* __restrict__ ubuf, const float* __restrict__ subuf,
                                 const float* __restrict__ c0buf, const float* __restrict__ vobuf,
                                 const float* __restrict__ ob, const int rowbase) {
    statsattn_body(blockIdx.x, threadIdx.x, rowbase, x, stats, mixA, pbufH,
                   ubuf, subuf, c0buf, vobuf, ob);
}

// ==== 256x256 8-phase counted-vmcnt GEMM (T2+T3+T4+T5) ===================
// AMODE 0: A = A0 (ld 1024)                          [mix2, NT=16]
// AMODE 1: A = [A0(ld1024, kt<8) | A1 ctx broadcast] [concat, NT=12]
// AMODE 2: A = [A0(ld1024, kt<16) | A1(ld512)]       [mix1, NT=24]
template<int AMODE, int NT, bool RELU>
__launch_bounds__(512, 2)
__global__ void mix_gemm8(const u16* __restrict__ A0, const u16* __restrict__ A1,
                          const u16* __restrict__ Wb, const float* __restrict__ bias,
                          u16* __restrict__ out, const int ldo) {
    constexpr int BLD = NT * 64;                 // B leading dim = K
    constexpr int NIT = NT / 2;
    extern __shared__ __align__(16) u16 S[];     // 65536 u16 = 128 KiB
    u16* As = S;
    u16* Bs = S + 32768;
    const int tid = threadIdx.x;
    const int l = tid & 63;
    const int w = tid >> 6;
    const int wm = w >> 2, wn = w & 3;
    const int quad = l >> 4, lc = l & 15;
    const size_t m0 = (size_t)blockIdx.x * 256;
    const int n0 = blockIdx.y * 256;
    const int bidx = (int)(m0 >> 12);

    // staging: slot s = tid (+512); row r = s>>3, swizzled chunk (s&7)^(r&7)
    const int r0 = tid >> 3;
    const int r1 = (tid + 512) >> 3;
    const int c0s = ((tid & 7) ^ (r0 & 7)) * 8;
    const int c1s = ((tid & 7) ^ (r1 & 7)) * 8;

    auto stA = [&](int kt, int h, int buf) {
        u16* dst = As + (buf * 2 + h) * 8192;
        if constexpr (AMODE == 0) {
            async16(A0 + (m0 + h * 128 + r0) * 1024 + kt * 64 + c0s, dst + tid * 8);
            async16(A0 + (m0 + h * 128 + r1) * 1024 + kt * 64 + c1s, dst + (tid + 512) * 8);
        } else if constexpr (AMODE == 1) {
            if (kt < 8) {
                async16(A0 + (m0 + h * 128 + r0) * 1024 + kt * 64 + c0s, dst + tid * 8);
                async16(A0 + (m0 + h * 128 + r1) * 1024 + kt * 64 + c1s, dst + (tid + 512) * 8);
            } else {
                async16(A1 + bidx * 256 + (kt - 8) * 64 + c0s, dst + tid * 8);
                async16(A1 + bidx * 256 + (kt - 8) * 64 + c1s, dst + (tid + 512) * 8);
            }
        } else {
            if (kt < 16) {
                async16(A0 + (m0 + h * 128 + r0) * 1024 + kt * 64 + c0s, dst + tid * 8);
                async16(A0 + (m0 + h * 128 + r1) * 1024 + kt * 64 + c1s, dst + (tid + 512) * 8);
            } else {
                async16(A1 + (m0 + h * 128 + r0) * 512 + (kt - 16) * 64 + c0s, dst + tid * 8);
                async16(A1 + (m0 + h * 128 + r1) * 512 + (kt - 16) * 64 + c1s, dst + (tid + 512) * 8);
            }
        }
    };
    auto stB = [&](int kt, int h, int buf) {
        u16* dst = Bs + (buf * 2 + h) * 8192;
        async16(Wb + (size_t)(n0 + h * 128 + r0) * BLD + kt * 64 + c0s, dst + tid * 8);
        async16(Wb + (size_t)(n0 + h * 128 + r1) * BLD + kt * 64 + c1s, dst + (tid + 512) * 8);
    };

    bf16x8 a_[4][2], b_[2][2][2];
    f32x4 acc[8][4];
    #pragma unroll
    for (int i = 0; i < 8; i++)
        #pragma unroll
        for (int j = 0; j < 4; j++) acc[i][j] = (f32x4){0.f, 0.f, 0.f, 0.f};

    auto rdA = [&](int buf, int qi) {
        const u16* Ab = As + (buf * 2 + wm) * 8192;
        #pragma unroll
        for (int ii = 0; ii < 4; ii++) {
            const int r = (qi * 4 + ii) * 16 + lc;
            #pragma unroll
            for (int kk = 0; kk < 2; kk++) {
                const int cs = (kk * 4 + quad) ^ (r & 7);
                a_[ii][kk] = *(const bf16x8*)&Ab[r * 64 + cs * 8];
            }
        }
    };
    auto rdB = [&](int buf, int qj) {
        #pragma unroll
        for (int jj = 0; jj < 2; jj++) {
            const int nr = wn * 64 + (qj * 2 + jj) * 16 + lc;
            const int hb = nr >> 7, r = nr & 127;
            const u16* Bb = Bs + (buf * 2 + hb) * 8192;
            #pragma unroll
            for (int kk = 0; kk < 2; kk++) {
                const int cs = (kk * 4 + quad) ^ (r & 7);
                b_[qj][jj][kk] = *(const bf16x8*)&Bb[r * 64 + cs * 8];
            }
        }
    };
    auto mfma16 = [&](int qi, int qj) {
        __builtin_amdgcn_s_setprio(1);
        #pragma unroll
        for (int ii = 0; ii < 4; ii++)
            #pragma unroll
            for (int jj = 0; jj < 2; jj++)
                #pragma unroll
                for (int kk = 0; kk < 2; kk++)
                    acc[qi * 4 + ii][qj * 2 + jj] = __builtin_amdgcn_mfma_f32_16x16x32_bf16(
                        a_[ii][kk], b_[qj][jj][kk], acc[qi * 4 + ii][qj * 2 + jj], 0, 0, 0);
        __builtin_amdgcn_s_setprio(0);
    };

    // prologue: K-tile 0 -> buf0 (4 half-tiles), K-tile 1 A-h0 -> buf1
    stA(0, 0, 0); stA(0, 1, 0); stB(0, 0, 0); stB(0, 1, 0);
    stA(1, 0, 1);
    WAITV(2); BARRIER();

    for (int it = 0; it < NIT; it++) {
        const int tb = 2 * it + 1;               // odd K-tile of this iter
        const bool more = (it < NIT - 1);
        // -- K-tile 2*it from buf0 --
        // ph1
        rdA(0, 0); rdB(0, 0);
        stA(tb, 1, 1);
        BARRIER(); mfma16(0, 0);
        // ph2
        rdB(0, 1);
        stB(tb, 0, 1);
        BARRIER(); mfma16(0, 1);
        // ph3
        rdA(0, 1);
        stB(tb, 1, 1);
        BARRIER(); mfma16(1, 1);
        BARRIER();                               // buf0-A reads retired before ph4 stage
        // ph4
        if (more) { stA(tb + 1, 0, 0); WAITV(2); }
        else      { WAITV(0); }
        BARRIER(); mfma16(1, 0);
        // -- K-tile tb from buf1 --
        // ph5
        rdA(1, 0); rdB(1, 0);
        if (more) stA(tb + 1, 1, 0);
        BARRIER(); mfma16(0, 0);
        // ph6
        rdB(1, 1);
        if (more) stB(tb + 1, 0, 0);
        BARRIER(); mfma16(0, 1);
        // ph7
        rdA(1, 1);
        if (more) stB(tb + 1, 1, 0);
        BARRIER(); mfma16(1, 1);
        BARRIER();                               // buf1-A reads retired before ph8 stage
        // ph8
        if (more) { stA(tb + 2, 0, 1); WAITV(2); }
        BARRIER(); mfma16(1, 0);
    }

    // epilogue: bias + optional relu, LDS transpose, coalesced bf16 store
    BARRIER();
    float bv[4];
    #pragma unroll
    for (int j = 0; j < 4; j++) bv[j] = bias[n0 + wn * 64 + j * 16 + lc];
    #pragma unroll
    for (int p = 0; p < 2; p++) {
        if (p) BARRIER();
        if (wm == p) {
            #pragma unroll
            for (int i = 0; i < 8; i++)
                #pragma unroll
                for (int j = 0; j < 4; j++)
                    #pragma unroll
                    for (int reg = 0; reg < 4; reg++) {
                        float vv = acc[i][j][reg] + bv[j];
                        if (RELU) vv = fmaxf(vv, 0.f);
                        S[(i * 16 + quad * 4 + reg) * 264 + wn * 64 + j * 16 + lc] = f2bf(vv);
                    }
        }
        LGKM0(); BARRIER();
        #pragma unroll
        for (int kq = 0; kq < 8; kq++) {
            const int cix = tid + kq * 512;      // 0..4095
            const int row = cix >> 5, ch = cix & 31;
            *(uint4*)(out + (m0 + p * 128 + row) * (size_t)ldo + n0 + ch * 8)
                = *(const uint4*)&S[row * 264 + ch * 8];
        }
    }
}

// ==== final: upd_c = LN(bufc); LN(base + gate*mask*(upd_c+upd_a)) ========
__global__ void final_kernel(const u16* __restrict__ mixA, const float* __restrict__ stats,
                             const u16* __restrict__ bufc,
                             const float* __restrict__ cg_, const float* __restrict__ cb,
                             const float* __restrict__ gb1, const float* __restrict__ betab,
                             const float* __restrict__ gateb, const int* __restrict__ mask,
                             const float* __restrict__ fg, const float* __restrict__ fb,
                             const float* __restrict__ og, const float* __restrict__ ob,
                             float* __restrict__ out) {
    const int wave = threadIdx.x >> 6, lane = threadIdx.x & 63;
    const size_t row = (size_t)blockIdx.x * 4 + wave;
    const int b = (int)(row >> 12);
    const int c0 = lane * 8;
    float xv[8], uc[8], ua[8];
    load8(mixA + row * 1024 + c0, xv);          // xbf
    load8(mixA + row * 1024 + 512 + c0, ua);    // upd_a
    load8(bufc + row * 512 + c0, uc);           // relu'd concat out (pre-LN)
    float sc = 0.f, ssc = 0.f;
    #pragma unroll
    for (int e = 0; e < 8; e++) { sc += uc[e]; ssc += uc[e] * uc[e]; }
    for (int m = 1; m < 64; m <<= 1) { sc += __shfl_xor(sc, m, 64); ssc += __shfl_xor(ssc, m, 64); }
    const float mc = sc * (1.f / 512.f);
    const float rc = rsqrtf(ssc * (1.f / 512.f) - mc * mc + 1e-5f);
    const float mean = stats[row * 2], rstd = stats[row * 2 + 1];
    const float mf = (mask[row] != 0) ? 1.f : 0.f;
    float y[8];
    float s = 0.f, ss = 0.f;
    #pragma unroll
    for (int e = 0; e < 8; e++) {
        int c = c0 + e;
        float ucn = (uc[e] - mc) * rc * cg_[c] + cb[c];
        float xh = (xv[e] - mean) * rstd;
        float base = gb1[b * 512 + c] * (xh * fg[c] + fb[c]) + betab[b * 512 + c];
        float yv = base + gateb[b * 512 + c] * mf * (ucn + ua[e]);
        y[e] = yv; s += yv; ss += yv * yv;
    }
    for (int m = 1; m < 64; m <<= 1) { s += __shfl_xor(s, m, 64); ss += __shfl_xor(ss, m, 64); }
    float mean2 = s * (1.f / 512.f);
    float rstd2 = rsqrtf(ss * (1.f / 512.f) - mean2 * mean2 + 1e-5f);
    float o[8];
    #pragma unroll
    for (int e = 0; e < 8; e++) {
        int c = c0 + e;
        o[e] = (y[e] - mean2) * rstd2 * og[c] + ob[c];
    }
    *(float4*)(out + row * 512 + c0)     = make_float4(o[0], o[1], o[2], o[3]);
    *(float4*)(out + row * 512 + c0 + 4) = make_float4(o[4], o[5], o[6], o[7]);
}

extern "C" void kernel_launch(void* const* d_in, const int* in_sizes, int n_in,
                              void* d_out, int out_size, void* d_ws, size_t ws_size,
                              hipStream_t stream) {
    const float* x          = (const float*)d_in[0];
    const float* context    = (const float*)d_in[1];
    const int*   mask       = (const int*)d_in[2];
    const float* film_ln_g  = (const float*)d_in[3];
    const float* film_ln_b  = (const float*)d_in[4];
    const float* film_w     = (const float*)d_in[5];
    const float* film_b     = (const float*)d_in[6];
    const float* concat_w   = (const float*)d_in[7];
    const float* concat_b   = (const float*)d_in[8];
    const float* concat_ln_g= (const float*)d_in[9];
    const float* concat_ln_b= (const float*)d_in[10];
    const float* ctx_w1     = (const float*)d_in[11];
    const float* ctx_b1     = (const float*)d_in[12];
    const float* ctx_w2     = (const float*)d_in[13];
    const float* ctx_b2     = (const float*)d_in[14];
    const float* q_ln_g     = (const float*)d_in[15];
    const float* q_ln_b     = (const float*)d_in[16];
    const float* in_proj_w  = (const float*)d_in[17];
    const float* in_proj_b  = (const float*)d_in[18];
    const float* out_proj_w = (const float*)d_in[19];
    const float* out_proj_b = (const float*)d_in[20];
    const float* mix_w1     = (const float*)d_in[21];
    const float* mix_b1     = (const float*)d_in[22];
    const float* mix_w2     = (const float*)d_in[23];
    const float* mix_b2     = (const float*)d_in[24];
    const float* out_ln_g   = (const float*)d_in[25];
    const float* out_ln_b   = (const float*)d_in[26];
    const float* gate_w     = (const float*)d_in[27];
    const float* gate_b     = (const float*)d_in[28];
    float* out = (float*)d_out;

    // ---- workspace layout (~150 MB, unchanged) ----
    float* gb1    = (float*)d_ws;            // 4096
    float* betab  = gb1 + 4096;
    float* gateb  = betab + 4096;
    float* kbuf   = gateb + 4096;            // 8192
    float* vbuf   = kbuf + 8192;
    float* bqp    = vbuf + 8192;             // 512
    float* hbuf   = bqp + 512;               // 4096
    float* tokbuf = hbuf + 4096;             // 8192
    float* ubuf   = tokbuf + 8192;           // 16384
    float* vobuf  = ubuf + 16384;            // 16384
    float* subuf  = vobuf + 16384;           // 32
    float* c0buf  = subuf + 32;              // 32
    float* stats  = c0buf + 32;              // 65536
    u16* ctxbf = (u16*)(stats + 65536);      // 2048
    u16* cwbf  = ctxbf + 2048;               // 393216
    u16* m1bf  = cwbf + 393216;              // 1572864
    u16* m2bf  = m1bf + 1572864;             // 524288
    u16* mixA  = m2bf + 524288;                        // 32768*1024 [xbf | ao->upd_a]
    u16* bufh  = mixA + (size_t)N_TOK * 1024;          // 32768*1024 full h
    u16* bufc  = bufh;                                 // alias: bufh dead after mix2
    u16* pbufH = bufh + (size_t)N_TOK * 1024;          // 16384*512  x*ao (per half)

    static bool attr_set = false;
    if (!attr_set) {
        hipFuncSetAttribute(reinterpret_cast<const void*>(&mix_gemm8<2, 24, true>),
                            hipFuncAttributeMaxDynamicSharedMemorySize, 131072);
        hipFuncSetAttribute(reinterpret_cast<const void*>(&mix_gemm8<0, 16, false>),
                            hipFuncAttributeMaxDynamicSharedMemorySize, 131072);
        hipFuncSetAttribute(reinterpret_cast<const void*>(&mix_gemm8<1, 12, true>),
                            hipFuncAttributeMaxDynamicSharedMemorySize, 131072);
        attr_set = true;
    }

    // cooperative fused front-end (prep, ctx_a..d, statsattn h=0)
    {
        void* kargs[] = {
            (void*)&in_proj_w, (void*)&in_proj_b, (void*)&q_ln_b,
            (void*)&concat_w, (void*)&mix_w1, (void*)&mix_w2,
            (void*)&context,
            (void*)&bqp, (void*)&cwbf, (void*)&m1bf, (void*)&m2bf, (void*)&ctxbf,
            (void*)&film_w, (void*)&film_b,
            (void*)&gate_w, (void*)&gate_b,
            (void*)&ctx_w1, (void*)&ctx_b1,
            (void*)&gb1, (void*)&betab, (void*)&gateb, (void*)&hbuf,
            (void*)&ctx_w2, (void*)&ctx_b2, (void*)&tokbuf,
            (void*)&kbuf, (void*)&vbuf,
            (void*)&out_proj_w, (void*)&q_ln_g,
            (void*)&ubuf, (void*)&vobuf, (void*)&subuf, (void*)&c0buf,
            (void*)&x, (void*)&stats, (void*)&mixA, (void*)&pbufH,
            (void*)&out_proj_b };
        hipLaunchCooperativeKernel(reinterpret_cast<const void*>(&ctx_fused),
                                   dim3(512), dim3(256), kargs, 0, stream);
    }

    // mix1 half 0 (statsattn h=0 already done inside ctx_fused)
    mix_gemm8<2, 24, true><<<dim3(64, 4), 512, 131072, stream>>>(
        mixA, pbufH, m1bf, mix_b1, bufh, 1024);
    // half 1
    statsattn_kernel<<<HALF_ROWS / 8, 256, 0, stream>>>(
        x, stats, mixA, pbufH, ubuf, subuf, c0buf, vobuf, out_proj_b, HALF_ROWS);
    mix_gemm8<2, 24, true><<<dim3(64, 4), 512, 131072, stream>>>(
        mixA + (size_t)HALF_ROWS * 1024, pbufH, m1bf, mix_b1,
        bufh + (size_t)HALF_ROWS * 1024, 1024);

    // mix2: single full-height dispatch, 256 blocks
    mix_gemm8<0, 16, false><<<dim3(128, 2), 512, 131072, stream>>>(
        bufh, nullptr, m2bf, mix_b2, mixA + 512, 1024);

    // concat: relu([x|ctx] @ concat_w^T + b) -> bufc (aliases bufh; LN in final)
    mix_gemm8<1, 12, true><<<dim3(128, 2), 512, 131072, stream>>>(
        mixA, ctxbf, cwbf, concat_b, bufc, 512);

    final_kernel<<<N_TOK / 4, 256, 0, stream>>>(mixA, stats, bufc,
                                                concat_ln_g, concat_ln_b,
                                                gb1, betab, gateb, mask,
                                                film_ln_g, film_ln_b,
                                                out_ln_g, out_ln_b, out);
    (void)in_sizes; (void)n_in; (void)out_size; (void)ws_size;
}

// Round 4
// 424.852 us; speedup vs baseline: 1.9616x; 1.9616x over previous
//
#include <hip/hip_runtime.h>
#include <hip/hip_bf16.h>

// HybridBridge round 10: revert cooperative fusion (R3: grid.sync cost ~100us
// each). Back to R2 structure + (a) deeper-prefetch 8-phase GEMM: stage->
// consume distance >=3 phases, WAITV(4) over loads issued >=2 phases earlier
// (T4 "never drain"); (b) prep+ctx_a merged (independent, no sync).
// B=8, L=4096, D=512, C=256, T=2, H=2, HD=256. N = 32768 rows.

#define N_TOK 32768
#define HALF_ROWS 16384

typedef unsigned short u16;
typedef __attribute__((ext_vector_type(8))) __bf16 bf16x8;
typedef __attribute__((ext_vector_type(4))) float f32x4;

__device__ __forceinline__ float bf2f(unsigned int h) { return __uint_as_float(h << 16); }
__device__ __forceinline__ u16 f2bf(float f) {
    unsigned int u = __float_as_uint(f);
    u += 0x7FFFu + ((u >> 16) & 1u);   // RNE
    return (u16)(u >> 16);
}
__device__ __forceinline__ void load8(const u16* p, float* v) {
    uint4 u = *(const uint4*)p;
    v[0] = bf2f(u.x & 0xffffu); v[1] = bf2f(u.x >> 16);
    v[2] = bf2f(u.y & 0xffffu); v[3] = bf2f(u.y >> 16);
    v[4] = bf2f(u.z & 0xffffu); v[5] = bf2f(u.z >> 16);
    v[6] = bf2f(u.w & 0xffffu); v[7] = bf2f(u.w >> 16);
}
__device__ __forceinline__ uint4 pack8(const float* v) {
    uint4 u;
    u.x = (unsigned)f2bf(v[0]) | ((unsigned)f2bf(v[1]) << 16);
    u.y = (unsigned)f2bf(v[2]) | ((unsigned)f2bf(v[3]) << 16);
    u.z = (unsigned)f2bf(v[4]) | ((unsigned)f2bf(v[5]) << 16);
    u.w = (unsigned)f2bf(v[6]) | ((unsigned)f2bf(v[7]) << 16);
    return u;
}
__device__ __forceinline__ void async16(const u16* g, u16* lds) {
    __builtin_amdgcn_global_load_lds(
        (const __attribute__((address_space(1))) unsigned int*)g,
        (__attribute__((address_space(3))) unsigned int*)lds, 16, 0, 0);
}

#define FENCE() asm volatile("" ::: "memory")
#define BARRIER() do { FENCE(); __builtin_amdgcn_s_barrier(); FENCE(); } while (0)
#define WAITV(n) asm volatile("s_waitcnt vmcnt(" #n ")" ::: "memory")
#define LGKM0()  asm volatile("s_waitcnt lgkmcnt(0)" ::: "memory")

// ==== phase bodies =======================================================

__device__ void prep_body(unsigned bid, int tid,
                          const float* __restrict__ in_proj_w,
                          const float* __restrict__ in_proj_b,
                          const float* __restrict__ qb,
                          const float* __restrict__ concat_w,
                          const float* __restrict__ mix_w1,
                          const float* __restrict__ mix_w2,
                          const float* __restrict__ context,
                          float* __restrict__ bqp,
                          u16* __restrict__ cwbf, u16* __restrict__ m1bf,
                          u16* __restrict__ m2bf, u16* __restrict__ ctxbf) {
    if (bid < 128) {
        const int wave = tid >> 6, lane = tid & 63;
        const int j = bid * 4 + wave;
        const int i = lane * 8;
        float4 w0 = *(const float4*)(in_proj_w + (size_t)j * 512 + i);
        float4 w1 = *(const float4*)(in_proj_w + (size_t)j * 512 + i + 4);
        float4 b0 = *(const float4*)(qb + i);
        float4 b1 = *(const float4*)(qb + i + 4);
        float p1 = w0.x*b0.x + w0.y*b0.y + w0.z*b0.z + w0.w*b0.w
                 + w1.x*b1.x + w1.y*b1.y + w1.z*b1.z + w1.w*b1.w;
        for (int m = 1; m < 64; m <<= 1) p1 += __shfl_xor(p1, m, 64);
        if (lane == 0) bqp[j] = in_proj_b[j] + p1;
    } else if (bid < 320) {
        int i = (bid - 128) * 256 + tid;           // < 49152
        const float* s = concat_w + (size_t)i * 8;
        float4 a = *(const float4*)s;
        float4 b = *(const float4*)(s + 4);
        float v[8] = {a.x, a.y, a.z, a.w, b.x, b.y, b.z, b.w};
        *(uint4*)(cwbf + (size_t)i * 8) = pack8(v);
    } else if (bid < 576) {
        int i = (bid - 320) * 256 + tid;           // < 65536
        const float* s = mix_w2 + (size_t)i * 8;
        float4 a = *(const float4*)s;
        float4 b = *(const float4*)(s + 4);
        float v[8] = {a.x, a.y, a.z, a.w, b.x, b.y, b.z, b.w};
        *(uint4*)(m2bf + (size_t)i * 8) = pack8(v);
    } else if (bid < 1344) {
        int idx = (bid - 576) * 256 + tid;         // < 196608
        int n = idx / 192;
        int k = (idx - n * 192) * 8;
        const float* base = mix_w1 + (size_t)n * 2048;
        float v[8];
        if (k < 512) {
            #pragma unroll
            for (int e = 0; e < 8; e++) v[e] = base[k + e] + base[1024 + k + e];
        } else if (k < 1024) {
            #pragma unroll
            for (int e = 0; e < 8; e++) v[e] = base[k + e] - base[512 + k + e];
        } else {
            #pragma unroll
            for (int e = 0; e < 8; e++) v[e] = base[512 + k + e];
        }
        *(uint4*)(m1bf + (size_t)n * 1536 + k) = pack8(v);
    } else {
        for (int i = tid; i < 2048; i += 256)
            ctxbf[i] = f2bf(context[i]);
    }
}

__device__ void ctx_a_body(unsigned task, int tid,
                           const float* __restrict__ context,
                           const float* __restrict__ film_w, const float* __restrict__ film_b,
                           const float* __restrict__ gate_w, const float* __restrict__ gate_b,
                           const float* __restrict__ ctx_w1, const float* __restrict__ ctx_b1,
                           float* __restrict__ gb1, float* __restrict__ betab,
                           float* __restrict__ gateb, float* __restrict__ hbuf) {
    const int wave = tid >> 6, lane = tid & 63;
    const int widx = (int)task * 4 + wave;        // 0..16383
    const int b   = widx >> 11;
    const int j2  = widx & 2047;
    const int cat = j2 >> 9;
    const int j   = j2 & 511;
    const float* wrow;
    if      (cat == 0) wrow = film_w + (size_t)j * 256;
    else if (cat == 1) wrow = film_w + (size_t)(512 + j) * 256;
    else if (cat == 2) wrow = gate_w + (size_t)j * 256;
    else               wrow = ctx_w1 + (size_t)j * 256;
    float4 wv = *(const float4*)(wrow + lane * 4);
    float4 cv = *(const float4*)(context + b * 256 + lane * 4);
    float s = wv.x * cv.x + wv.y * cv.y + wv.z * cv.z + wv.w * cv.w;
    for (int m = 1; m < 64; m <<= 1) s += __shfl_xor(s, m, 64);
    if (lane == 0) {
        if      (cat == 0) gb1[b * 512 + j]   = 1.0f + s + film_b[j];
        else if (cat == 1) betab[b * 512 + j] = s + film_b[512 + j];
        else if (cat == 2) gateb[b * 512 + j] = 1.f / (1.f + expf(-(s + gate_b[j])));
        else {
            float hv = s + ctx_b1[j];
            hbuf[b * 512 + j] = 0.5f * hv * (1.0f + erff(hv * 0.70710678118654752f));
        }
    }
}

// merged prep + ctx_a (independent work, pure grid concatenation)
__global__ void prep_ctxa_kernel(const float* __restrict__ in_proj_w,
                                 const float* __restrict__ in_proj_b,
                                 const float* __restrict__ qb,
                                 const float* __restrict__ concat_w,
                                 const float* __restrict__ mix_w1,
                                 const float* __restrict__ mix_w2,
                                 const float* __restrict__ context,
                                 float* __restrict__ bqp,
                                 u16* __restrict__ cwbf, u16* __restrict__ m1bf,
                                 u16* __restrict__ m2bf, u16* __restrict__ ctxbf,
                                 const float* __restrict__ film_w, const float* __restrict__ film_b,
                                 const float* __restrict__ gate_w, const float* __restrict__ gate_b,
                                 const float* __restrict__ ctx_w1, const float* __restrict__ ctx_b1,
                                 float* __restrict__ gb1, float* __restrict__ betab,
                                 float* __restrict__ gateb, float* __restrict__ hbuf) {
    if (blockIdx.x < 1345)
        prep_body(blockIdx.x, threadIdx.x, in_proj_w, in_proj_b, qb, concat_w,
                  mix_w1, mix_w2, context, bqp, cwbf, m1bf, m2bf, ctxbf);
    else
        ctx_a_body(blockIdx.x - 1345, threadIdx.x, context, film_w, film_b,
                   gate_w, gate_b, ctx_w1, ctx_b1, gb1, betab, gateb, hbuf);
}

// ==== context stage B ====================================================
__global__ void ctx_stage_b(const float* __restrict__ hbuf,
                            const float* __restrict__ ctx_w2, const float* __restrict__ ctx_b2,
                            float* __restrict__ tokbuf) {
    const int wave = threadIdx.x >> 6, lane = threadIdx.x & 63;
    const int widx = blockIdx.x * 4 + wave;       // 0..8191
    const int b = widx >> 10;
    const int j = widx & 1023;
    const float* wrow = ctx_w2 + (size_t)j * 512 + lane * 8;
    const float* hr   = hbuf + b * 512 + lane * 8;
    float4 w0 = *(const float4*)wrow, w1 = *(const float4*)(wrow + 4);
    float4 h0 = *(const float4*)hr,   h1 = *(const float4*)(hr + 4);
    float s = w0.x*h0.x + w0.y*h0.y + w0.z*h0.z + w0.w*h0.w
            + w1.x*h1.x + w1.y*h1.y + w1.z*h1.z + w1.w*h1.w;
    for (int m = 1; m < 64; m <<= 1) s += __shfl_xor(s, m, 64);
    if (lane == 0) tokbuf[b * 1024 + j] = s + ctx_b2[j];
}

// ==== context stage C ====================================================
__global__ void ctx_stage_c(const float* __restrict__ tokbuf,
                            const float* __restrict__ in_proj_w, const float* __restrict__ in_proj_b,
                            float* __restrict__ kbuf, float* __restrict__ vbuf) {
    const int wave = threadIdx.x >> 6, lane = threadIdx.x & 63;
    const int widx = blockIdx.x * 4 + wave;       // 0..16383
    const int b  = widx >> 11;
    const int r  = widx & 2047;
    const int t  = r >> 10;
    const int kv = (r >> 9) & 1;
    const int j  = r & 511;
    const float* wrow = in_proj_w + (size_t)(512 + kv * 512 + j) * 512 + lane * 8;
    const float* tk   = tokbuf + (b * 2 + t) * 512 + lane * 8;
    float4 w0 = *(const float4*)wrow, w1 = *(const float4*)(wrow + 4);
    float4 t0 = *(const float4*)tk,   t1 = *(const float4*)(tk + 4);
    float s = w0.x*t0.x + w0.y*t0.y + w0.z*t0.z + w0.w*t0.w
            + w1.x*t1.x + w1.y*t1.y + w1.z*t1.z + w1.w*t1.w;
    for (int m = 1; m < 64; m <<= 1) s += __shfl_xor(s, m, 64);
    if (lane == 0) {
        float v = s + in_proj_b[512 + kv * 512 + j];
        if (kv == 0) kbuf[(b * 2 + t) * 512 + j] = v;
        else         vbuf[(b * 2 + t) * 512 + j] = v;
    }
}

// ==== context stage D: u/su/c0 (bid<32) and vo (bid>=32) =================
__global__ void ctx_stage_d(const float* __restrict__ in_proj_w,
                            const float* __restrict__ out_proj_w,
                            const float* __restrict__ qg, const float* __restrict__ bqp,
                            const float* __restrict__ kbuf, const float* __restrict__ vbuf,
                            float* __restrict__ ubuf, float* __restrict__ vobuf,
                            float* __restrict__ subuf, float* __restrict__ c0buf) {
    const int tid = threadIdx.x;
    __shared__ float sh[256];
    __shared__ float red[256];
    if (blockIdx.x < 32) {
        const int bid = blockIdx.x;
        const int b = bid >> 2, idx = bid & 3;
        const int t = idx >> 1, h = idx & 1;
        sh[tid] = kbuf[(b * 2 + t) * 512 + h * 256 + tid];
        __syncthreads();
        float a0 = 0.f, a1 = 0.f;
        #pragma unroll 4
        for (int dd = 0; dd < 256; dd++) {
            const float kv = sh[dd];
            const float* wr = in_proj_w + (size_t)(h * 256 + dd) * 512;
            a0 += kv * wr[tid];
            a1 += kv * wr[tid + 256];
        }
        float u0 = a0 * qg[tid], u1 = a1 * qg[tid + 256];
        ubuf[bid * 512 + tid]       = u0;
        ubuf[bid * 512 + tid + 256] = u1;
        red[tid] = u0 + u1;
        __syncthreads();
        for (int s = 128; s > 0; s >>= 1) { if (tid < s) red[tid] += red[tid + s]; __syncthreads(); }
        if (tid == 0) subuf[bid] = red[0];
        __syncthreads();
        red[tid] = bqp[h * 256 + tid] * sh[tid];
        __syncthreads();
        for (int s = 128; s > 0; s >>= 1) { if (tid < s) red[tid] += red[tid + s]; __syncthreads(); }
        if (tid == 0) c0buf[bid] = red[0];
    } else {
        const int bid = blockIdx.x - 32;
        const int b = bid >> 2, idx = bid & 3;
        const int t = idx >> 1, h = idx & 1;
        sh[tid] = vbuf[(b * 2 + t) * 512 + h * 256 + tid];
        __syncthreads();
        const float* w0 = out_proj_w + (size_t)tid * 512 + h * 256;
        const float* w1 = out_proj_w + (size_t)(tid + 256) * 512 + h * 256;
        float acc0 = 0.f, acc1 = 0.f;
        #pragma unroll 2
        for (int dd = 0; dd < 256; dd += 4) {
            float4 x0 = *(const float4*)(w0 + dd);
            float4 x1 = *(const float4*)(w1 + dd);
            acc0 += x0.x*sh[dd] + x0.y*sh[dd+1] + x0.z*sh[dd+2] + x0.w*sh[dd+3];
            acc1 += x1.x*sh[dd] + x1.y*sh[dd+1] + x1.z*sh[dd+2] + x1.w*sh[dd+3];
        }
        vobuf[bid * 512 + tid]       = acc0;
        vobuf[bid * 512 + tid + 256] = acc1;
    }
}

// ==== fused stats + attn, 2 rows per wave, half-range ====================
__global__ void statsattn_kernel(const float* __restrict__ x, float* __restrict__ stats,
                                 u16* __restrict__ mixA, u16* __restrict__ pbufH,
                                 const float* __restrict__ ubuf, const float* __restrict__ subuf,
                                 const float* __restrict__ c0buf, const float* __restrict__ vobuf,
                                 const float* __restrict__ ob, const int rowbase) {
    const int wave = threadIdx.x >> 6, lane = threadIdx.x & 63;
    const size_t lr = (size_t)blockIdx.x * 8 + wave * 2;   // local rows lr, lr+1
    const size_t gr = lr + rowbase;
    const int b = (int)(gr >> 12);                          // same for both rows
    float v[2][8], s[2] = {0.f, 0.f}, ss[2] = {0.f, 0.f};
    #pragma unroll
    for (int r = 0; r < 2; r++) {
        const float* xr = x + (gr + r) * 512 + lane * 8;
        float4 a = *(const float4*)xr;
        float4 c = *(const float4*)(xr + 4);
        v[r][0]=a.x; v[r][1]=a.y; v[r][2]=a.z; v[r][3]=a.w;
        v[r][4]=c.x; v[r][5]=c.y; v[r][6]=c.z; v[r][7]=c.w;
        #pragma unroll
        for (int e = 0; e < 8; e++) { s[r] += v[r][e]; ss[r] += v[r][e] * v[r][e]; }
    }
    float u[4][8];
    #pragma unroll
    for (int idx = 0; idx < 4; idx++) {
        const float* up = ubuf + (b * 4 + idx) * 512 + lane * 8;
        float4 u0 = *(const float4*)up, u1 = *(const float4*)(up + 4);
        u[idx][0]=u0.x; u[idx][1]=u0.y; u[idx][2]=u0.z; u[idx][3]=u0.w;
        u[idx][4]=u1.x; u[idx][5]=u1.y; u[idx][6]=u1.z; u[idx][7]=u1.w;
    }
    float sd[2][4];
    #pragma unroll
    for (int r = 0; r < 2; r++)
        #pragma unroll
        for (int idx = 0; idx < 4; idx++) {
            float acc = 0.f;
            #pragma unroll
            for (int e = 0; e < 8; e++) acc += v[r][e] * u[idx][e];
            sd[r][idx] = acc;
        }
    for (int m = 1; m < 64; m <<= 1) {
        #pragma unroll
        for (int r = 0; r < 2; r++) {
            s[r] += __shfl_xor(s[r], m, 64); ss[r] += __shfl_xor(ss[r], m, 64);
            #pragma unroll
            for (int idx = 0; idx < 4; idx++) sd[r][idx] += __shfl_xor(sd[r][idx], m, 64);
        }
    }
    float vo[4][8];
    #pragma unroll
    for (int idx = 0; idx < 4; idx++) {
        const float* vp = vobuf + (b * 4 + idx) * 512 + lane * 8;
        float4 v0 = *(const float4*)vp, v1 = *(const float4*)(vp + 4);
        vo[idx][0]=v0.x; vo[idx][1]=v0.y; vo[idx][2]=v0.z; vo[idx][3]=v0.w;
        vo[idx][4]=v1.x; vo[idx][5]=v1.y; vo[idx][6]=v1.z; vo[idx][7]=v1.w;
    }
    float obp[8];
    {
        const float* op = ob + lane * 8;
        float4 o0 = *(const float4*)op, o1 = *(const float4*)(op + 4);
        obp[0]=o0.x; obp[1]=o0.y; obp[2]=o0.z; obp[3]=o0.w;
        obp[4]=o1.x; obp[5]=o1.y; obp[6]=o1.z; obp[7]=o1.w;
    }
    #pragma unroll
    for (int r = 0; r < 2; r++) {
        const float mean = s[r] * (1.f / 512.f);
        const float rstd = rsqrtf(ss[r] * (1.f / 512.f) - mean * mean + 1e-5f);
        if (lane == 0) { stats[(gr + r) * 2] = mean; stats[(gr + r) * 2 + 1] = rstd; }
        float sc[4];
        #pragma unroll
        for (int idx = 0; idx < 4; idx++)
            sc[idx] = (rstd * (sd[r][idx] - mean * subuf[b * 4 + idx]) + c0buf[b * 4 + idx]) * (1.f / 16.f);
        float p[4];
        #pragma unroll
        for (int h = 0; h < 2; h++) {
            float s0 = sc[h], s1 = sc[2 + h];
            float mx = fmaxf(s0, s1);
            float e0 = expf(s0 - mx), e1 = expf(s1 - mx);
            float inv = 1.f / (e0 + e1);
            p[h] = e0 * inv; p[2 + h] = e1 * inv;
        }
        float o[8], pr[8];
        #pragma unroll
        for (int e = 0; e < 8; e++) {
            o[e] = p[0]*vo[0][e] + p[1]*vo[1][e] + p[2]*vo[2][e] + p[3]*vo[3][e] + obp[e];
            pr[e] = v[r][e] * o[e];
        }
        *(uint4*)(mixA + (gr + r) * 1024 + lane * 8)       = pack8(v[r]);
        *(uint4*)(mixA + (gr + r) * 1024 + 512 + lane * 8) = pack8(o);
        *(uint4*)(pbufH + (lr + r) * 512 + lane * 8)       = pack8(pr);
    }
}

// ==== 256x256 8-phase GEMM, deep-prefetch counted vmcnt (T2+T3+T4+T5) ====
// AMODE 0: A = A0 (ld 1024)                          [mix2, NT=16]
// AMODE 1: A = [A0(ld1024, kt<8) | A1 ctx broadcast] [concat, NT=12]
// AMODE 2: A = [A0(ld1024, kt<16) | A1(ld512)]       [mix1, NT=24]
// Stage map per iter (tiles t0=2it, t1=2it+1):
//   ph1/ph2: A(t1)->buf1   ph3/ph4: B(t0+2)->buf0 + WAITV(4)
//   ph5/ph6: A(t0+2)->buf0 ph7/ph8: B(t1+2)->buf1 + WAITV(4)
// Every WAITV(4) drains only loads issued >=2 phases earlier; every LDS
// overwrite is >=2 barriers after the region's last ds_read.
template<int AMODE, int NT, bool RELU>
__launch_bounds__(512, 2)
__global__ void mix_gemm8(const u16* __restrict__ A0, const u16* __restrict__ A1,
                          const u16* __restrict__ Wb, const float* __restrict__ bias,
                          u16* __restrict__ out, const int ldo) {
    constexpr int BLD = NT * 64;                 // B leading dim = K
    constexpr int NIT = NT / 2;
    extern __shared__ __align__(16) u16 S[];     // 65536 u16 = 128 KiB
    u16* As = S;
    u16* Bs = S + 32768;
    const int tid = threadIdx.x;
    const int l = tid & 63;
    const int w = tid >> 6;
    const int wm = w >> 2, wn = w & 3;
    const int quad = l >> 4, lc = l & 15;
    const size_t m0 = (size_t)blockIdx.x * 256;
    const int n0 = blockIdx.y * 256;
    const int bidx = (int)(m0 >> 12);

    // staging: slot s = tid (+512); row r = s>>3, swizzled chunk (s&7)^(r&7)
    const int r0 = tid >> 3;
    const int r1 = (tid + 512) >> 3;
    const int c0s = ((tid & 7) ^ (r0 & 7)) * 8;
    const int c1s = ((tid & 7) ^ (r1 & 7)) * 8;

    auto stA = [&](int kt, int h, int buf) {
        u16* dst = As + (buf * 2 + h) * 8192;
        if constexpr (AMODE == 0) {
            async16(A0 + (m0 + h * 128 + r0) * 1024 + kt * 64 + c0s, dst + tid * 8);
            async16(A0 + (m0 + h * 128 + r1) * 1024 + kt * 64 + c1s, dst + (tid + 512) * 8);
        } else if constexpr (AMODE == 1) {
            if (kt < 8) {
                async16(A0 + (m0 + h * 128 + r0) * 1024 + kt * 64 + c0s, dst + tid * 8);
                async16(A0 + (m0 + h * 128 + r1) * 1024 + kt * 64 + c1s, dst + (tid + 512) * 8);
            } else {
                async16(A1 + bidx * 256 + (kt - 8) * 64 + c0s, dst + tid * 8);
                async16(A1 + bidx * 256 + (kt - 8) * 64 + c1s, dst + (tid + 512) * 8);
            }
        } else {
            if (kt < 16) {
                async16(A0 + (m0 + h * 128 + r0) * 1024 + kt * 64 + c0s, dst + tid * 8);
                async16(A0 + (m0 + h * 128 + r1) * 1024 + kt * 64 + c1s, dst + (tid + 512) * 8);
            } else {
                async16(A1 + (m0 + h * 128 + r0) * 512 + (kt - 16) * 64 + c0s, dst + tid * 8);
                async16(A1 + (m0 + h * 128 + r1) * 512 + (kt - 16) * 64 + c1s, dst + (tid + 512) * 8);
            }
        }
    };
    auto stB = [&](int kt, int h, int buf) {
        u16* dst = Bs + (buf * 2 + h) * 8192;
        async16(Wb + (size_t)(n0 + h * 128 + r0) * BLD + kt * 64 + c0s, dst + tid * 8);
        async16(Wb + (size_t)(n0 + h * 128 + r1) * BLD + kt * 64 + c1s, dst + (tid + 512) * 8);
    };

    bf16x8 a_[4][2], b_[2][2][2];
    f32x4 acc[8][4];
    #pragma unroll
    for (int i = 0; i < 8; i++)
        #pragma unroll
        for (int j = 0; j < 4; j++) acc[i][j] = (f32x4){0.f, 0.f, 0.f, 0.f};

    auto rdA = [&](int buf, int qi) {
        const u16* Ab = As + (buf * 2 + wm) * 8192;
        #pragma unroll
        for (int ii = 0; ii < 4; ii++) {
            const int r = (qi * 4 + ii) * 16 + lc;
            #pragma unroll
            for (int kk = 0; kk < 2; kk++) {
                const int cs = (kk * 4 + quad) ^ (r & 7);
                a_[ii][kk] = *(const bf16x8*)&Ab[r * 64 + cs * 8];
            }
        }
    };
    auto rdB = [&](int buf, int qj) {
        #pragma unroll
        for (int jj = 0; jj < 2; jj++) {
            const int nr = wn * 64 + (qj * 2 + jj) * 16 + lc;
            const int hb = nr >> 7, r = nr & 127;
            const u16* Bb = Bs + (buf * 2 + hb) * 8192;
            #pragma unroll
            for (int kk = 0; kk < 2; kk++) {
                const int cs = (kk * 4 + quad) ^ (r & 7);
                b_[qj][jj][kk] = *(const bf16x8*)&Bb[r * 64 + cs * 8];
            }
        }
    };
    auto mfma16 = [&](int qi, int qj) {
        __builtin_amdgcn_s_setprio(1);
        #pragma unroll
        for (int ii = 0; ii < 4; ii++)
            #pragma unroll
            for (int jj = 0; jj < 2; jj++)
                #pragma unroll
                for (int kk = 0; kk < 2; kk++)
                    acc[qi * 4 + ii][qj * 2 + jj] = __builtin_amdgcn_mfma_f32_16x16x32_bf16(
                        a_[ii][kk], b_[qj][jj][kk], acc[qi * 4 + ii][qj * 2 + jj], 0, 0, 0);
        __builtin_amdgcn_s_setprio(0);
    };

    // prologue: tile0 -> buf0 (4 half-tiles) + tile1 B -> buf1 (2 half-tiles)
    stA(0, 0, 0); stA(0, 1, 0); stB(0, 0, 0); stB(0, 1, 0);
    stB(1, 0, 1); stB(1, 1, 1);
    WAITV(4); BARRIER();                         // tile0 complete; B(t1) in flight

    for (int it = 0; it < NIT; it++) {
        const int t0 = 2 * it, t1 = 2 * it + 1;
        const bool more = (it + 1 < NIT);
        // ph1: compute buf0 q(0,0); stage A(t1) h0 -> buf1
        rdA(0, 0); rdB(0, 0);
        stA(t1, 0, 1);
        BARRIER(); mfma16(0, 0);
        // ph2: stage A(t1) h1 -> buf1
        rdB(0, 1);
        stA(t1, 1, 1);
        BARRIER(); mfma16(0, 1);
        BARRIER();                               // buf0-B reads retired before ph3 overwrite
        // ph3: stage B(t0+2) h0 -> buf0
        rdA(0, 1);
        if (more) stB(t0 + 2, 0, 0);
        BARRIER(); mfma16(1, 1);
        // ph4: stage B(t0+2) h1 -> buf0; drain A(t1)+B(t1)
        if (more) { stB(t0 + 2, 1, 0); WAITV(4); }
        else      { WAITV(0); }
        BARRIER(); mfma16(1, 0);
        // ph5: compute buf1 q(0,0); stage A(t0+2) h0 -> buf0
        rdA(1, 0); rdB(1, 0);
        if (more) stA(t0 + 2, 0, 0);
        BARRIER(); mfma16(0, 0);
        // ph6: stage A(t0+2) h1 -> buf0
        rdB(1, 1);
        if (more) stA(t0 + 2, 1, 0);
        BARRIER(); mfma16(0, 1);
        BARRIER();                               // buf1-B reads retired before ph7 overwrite
        // ph7: stage B(t1+2) h0 -> buf1
        rdA(1, 1);
        if (more) stB(t1 + 2, 0, 1);
        BARRIER(); mfma16(1, 1);
        // ph8: stage B(t1+2) h1 -> buf1; drain B(t0+2)+A(t0+2)
        if (more) { stB(t1 + 2, 1, 1); WAITV(4); }
        BARRIER(); mfma16(1, 0);
    }

    // epilogue: bias + optional relu, LDS transpose, coalesced bf16 store
    BARRIER();
    float bv[4];
    #pragma unroll
    for (int j = 0; j < 4; j++) bv[j] = bias[n0 + wn * 64 + j * 16 + lc];
    #pragma unroll
    for (int p = 0; p < 2; p++) {
        if (p) BARRIER();
        if (wm == p) {
            #pragma unroll
            for (int i = 0; i < 8; i++)
                #pragma unroll
                for (int j = 0; j < 4; j++)
                    #pragma unroll
                    for (int reg = 0; reg < 4; reg++) {
                        float vv = acc[i][j][reg] + bv[j];
                        if (RELU) vv = fmaxf(vv, 0.f);
                        S[(i * 16 + quad * 4 + reg) * 264 + wn * 64 + j * 16 + lc] = f2bf(vv);
                    }
        }
        LGKM0(); BARRIER();
        #pragma unroll
        for (int kq = 0; kq < 8; kq++) {
            const int cix = tid + kq * 512;      // 0..4095
            const int row = cix >> 5, ch = cix & 31;
            *(uint4*)(out + (m0 + p * 128 + row) * (size_t)ldo + n0 + ch * 8)
                = *(const uint4*)&S[row * 264 + ch * 8];
        }
    }
}

// ==== final: upd_c = LN(bufc); LN(base + gate*mask*(upd_c+upd_a)) ========
__global__ void final_kernel(const u16* __restrict__ mixA, const float* __restrict__ stats,
                             const u16* __restrict__ bufc,
                             const float* __restrict__ cg_, const float* __restrict__ cb,
                             const float* __restrict__ gb1, const float* __restrict__ betab,
                             const float* __restrict__ gateb, const int* __restrict__ mask,
                             const float* __restrict__ fg, const float* __restrict__ fb,
                             const float* __restrict__ og, const float* __restrict__ ob,
                             float* __restrict__ out) {
    const int wave = threadIdx.x >> 6, lane = threadIdx.x & 63;
    const size_t row = (size_t)blockIdx.x * 4 + wave;
    const int b = (int)(row >> 12);
    const int c0 = lane * 8;
    float xv[8], uc[8], ua[8];
    load8(mixA + row * 1024 + c0, xv);          // xbf
    load8(mixA + row * 1024 + 512 + c0, ua);    // upd_a
    load8(bufc + row * 512 + c0, uc);           // relu'd concat out (pre-LN)
    float sc = 0.f, ssc = 0.f;
    #pragma unroll
    for (int e = 0; e < 8; e++) { sc += uc[e]; ssc += uc[e] * uc[e]; }
    for (int m = 1; m < 64; m <<= 1) { sc += __shfl_xor(sc, m, 64); ssc += __shfl_xor(ssc, m, 64); }
    const float mc = sc * (1.f / 512.f);
    const float rc = rsqrtf(ssc * (1.f / 512.f) - mc * mc + 1e-5f);
    const float mean = stats[row * 2], rstd = stats[row * 2 + 1];
    const float mf = (mask[row] != 0) ? 1.f : 0.f;
    float y[8];
    float s = 0.f, ss = 0.f;
    #pragma unroll
    for (int e = 0; e < 8; e++) {
        int c = c0 + e;
        float ucn = (uc[e] - mc) * rc * cg_[c] + cb[c];
        float xh = (xv[e] - mean) * rstd;
        float base = gb1[b * 512 + c] * (xh * fg[c] + fb[c]) + betab[b * 512 + c];
        float yv = base + gateb[b * 512 + c] * mf * (ucn + ua[e]);
        y[e] = yv; s += yv; ss += yv * yv;
    }
    for (int m = 1; m < 64; m <<= 1) { s += __shfl_xor(s, m, 64); ss += __shfl_xor(ss, m, 64); }
    float mean2 = s * (1.f / 512.f);
    float rstd2 = rsqrtf(ss * (1.f / 512.f) - mean2 * mean2 + 1e-5f);
    float o[8];
    #pragma unroll
    for (int e = 0; e < 8; e++) {
        int c = c0 + e;
        o[e] = (y[e] - mean2) * rstd2 * og[c] + ob[c];
    }
    *(float4*)(out + row * 512 + c0)     = make_float4(o[0], o[1], o[2], o[3]);
    *(float4*)(out + row * 512 + c0 + 4) = make_float4(o[4], o[5], o[6], o[7]);
}

extern "C" void kernel_launch(void* const* d_in, const int* in_sizes, int n_in,
                              void* d_out, int out_size, void* d_ws, size_t ws_size,
                              hipStream_t stream) {
    const float* x          = (const float*)d_in[0];
    const float* context    = (const float*)d_in[1];
    const int*   mask       = (const int*)d_in[2];
    const float* film_ln_g  = (const float*)d_in[3];
    const float* film_ln_b  = (const float*)d_in[4];
    const float* film_w     = (const float*)d_in[5];
    const float* film_b     = (const float*)d_in[6];
    const float* concat_w   = (const float*)d_in[7];
    const float* concat_b   = (const float*)d_in[8];
    const float* concat_ln_g= (const float*)d_in[9];
    const float* concat_ln_b= (const float*)d_in[10];
    const float* ctx_w1     = (const float*)d_in[11];
    const float* ctx_b1     = (const float*)d_in[12];
    const float* ctx_w2     = (const float*)d_in[13];
    const float* ctx_b2     = (const float*)d_in[14];
    const float* q_ln_g     = (const float*)d_in[15];
    const float* q_ln_b     = (const float*)d_in[16];
    const float* in_proj_w  = (const float*)d_in[17];
    const float* in_proj_b  = (const float*)d_in[18];
    const float* out_proj_w = (const float*)d_in[19];
    const float* out_proj_b = (const float*)d_in[20];
    const float* mix_w1     = (const float*)d_in[21];
    const float* mix_b1     = (const float*)d_in[22];
    const float* mix_w2     = (const float*)d_in[23];
    const float* mix_b2     = (const float*)d_in[24];
    const float* out_ln_g   = (const float*)d_in[25];
    const float* out_ln_b   = (const float*)d_in[26];
    const float* gate_w     = (const float*)d_in[27];
    const float* gate_b     = (const float*)d_in[28];
    float* out = (float*)d_out;

    // ---- workspace layout (~150 MB, unchanged) ----
    float* gb1    = (float*)d_ws;            // 4096
    float* betab  = gb1 + 4096;
    float* gateb  = betab + 4096;
    float* kbuf   = gateb + 4096;            // 8192
    float* vbuf   = kbuf + 8192;
    float* bqp    = vbuf + 8192;             // 512
    float* hbuf   = bqp + 512;               // 4096
    float* tokbuf = hbuf + 4096;             // 8192
    float* ubuf   = tokbuf + 8192;           // 16384
    float* vobuf  = ubuf + 16384;            // 16384
    float* subuf  = vobuf + 16384;           // 32
    float* c0buf  = subuf + 32;              // 32
    float* stats  = c0buf + 32;              // 65536
    u16* ctxbf = (u16*)(stats + 65536);      // 2048
    u16* cwbf  = ctxbf + 2048;               // 393216
    u16* m1bf  = cwbf + 393216;              // 1572864
    u16* m2bf  = m1bf + 1572864;             // 524288
    u16* mixA  = m2bf + 524288;                        // 32768*1024 [xbf | ao->upd_a]
    u16* bufh  = mixA + (size_t)N_TOK * 1024;          // 32768*1024 full h
    u16* bufc  = bufh;                                 // alias: bufh dead after mix2
    u16* pbufH = bufh + (size_t)N_TOK * 1024;          // 16384*512  x*ao (per half)

    static bool attr_set = false;
    if (!attr_set) {
        hipFuncSetAttribute(reinterpret_cast<const void*>(&mix_gemm8<2, 24, true>),
                            hipFuncAttributeMaxDynamicSharedMemorySize, 131072);
        hipFuncSetAttribute(reinterpret_cast<const void*>(&mix_gemm8<0, 16, false>),
                            hipFuncAttributeMaxDynamicSharedMemorySize, 131072);
        hipFuncSetAttribute(reinterpret_cast<const void*>(&mix_gemm8<1, 12, true>),
                            hipFuncAttributeMaxDynamicSharedMemorySize, 131072);
        attr_set = true;
    }

    prep_ctxa_kernel<<<5441, 256, 0, stream>>>(
        in_proj_w, in_proj_b, q_ln_b, concat_w, mix_w1, mix_w2, context,
        bqp, cwbf, m1bf, m2bf, ctxbf,
        film_w, film_b, gate_w, gate_b, ctx_w1, ctx_b1,
        gb1, betab, gateb, hbuf);
    ctx_stage_b<<<2048, 256, 0, stream>>>(hbuf, ctx_w2, ctx_b2, tokbuf);
    ctx_stage_c<<<4096, 256, 0, stream>>>(tokbuf, in_proj_w, in_proj_b, kbuf, vbuf);
    ctx_stage_d<<<64, 256, 0, stream>>>(in_proj_w, out_proj_w, q_ln_g, bqp,
                                        kbuf, vbuf, ubuf, vobuf, subuf, c0buf);

    // mix1 per half (pbufH reused); full bufh accumulates both halves
    for (int h = 0; h < 2; h++) {
        const int rowbase = h * HALF_ROWS;
        statsattn_kernel<<<HALF_ROWS / 8, 256, 0, stream>>>(
            x, stats, mixA, pbufH, ubuf, subuf, c0buf, vobuf, out_proj_b, rowbase);
        mix_gemm8<2, 24, true><<<dim3(64, 4), 512, 131072, stream>>>(
            mixA + (size_t)rowbase * 1024, pbufH, m1bf, mix_b1,
            bufh + (size_t)rowbase * 1024, 1024);
    }
    // mix2: single full-height dispatch, 256 blocks
    mix_gemm8<0, 16, false><<<dim3(128, 2), 512, 131072, stream>>>(
        bufh, nullptr, m2bf, mix_b2, mixA + 512, 1024);

    // concat: relu([x|ctx] @ concat_w^T + b) -> bufc (aliases bufh; LN in final)
    mix_gemm8<1, 12, true><<<dim3(128, 2), 512, 131072, stream>>>(
        mixA, ctxbf, cwbf, concat_b, bufc, 512);

    final_kernel<<<N_TOK / 4, 256, 0, stream>>>(mixA, stats, bufc,
                                                concat_ln_g, concat_ln_b,
                                                gb1, betab, gateb, mask,
                                                film_ln_g, film_ln_b,
                                                out_ln_g, out_ln_b, out);
    (void)in_sizes; (void)n_in; (void)out_size; (void)ws_size;
}

// Round 5
// 414.920 us; speedup vs baseline: 2.0085x; 1.0239x over previous
//
#include <hip/hip_runtime.h>
#include <hip/hip_bf16.h>

// HybridBridge round 11: dispatch-count attack without grid.sync (R3 lesson).
// - full pbuf (ws-checked, fallback to half path): 1x statsattn + 1x mix1
// - mix2+concat merged into one 512-block dispatch (bufc aliases dead pbuf)
// - ctx_d widened 64->128 blocks (j-split, subuf atomicAdd)
// - GEMM inner schedule = R2's proven 8-phase counted-vmcnt body (untouched)
// B=8, L=4096, D=512, C=256, T=2, H=2, HD=256. N = 32768 rows.

#define N_TOK 32768
#define HALF_ROWS 16384

typedef unsigned short u16;
typedef __attribute__((ext_vector_type(8))) __bf16 bf16x8;
typedef __attribute__((ext_vector_type(4))) float f32x4;

__device__ __forceinline__ float bf2f(unsigned int h) { return __uint_as_float(h << 16); }
__device__ __forceinline__ u16 f2bf(float f) {
    unsigned int u = __float_as_uint(f);
    u += 0x7FFFu + ((u >> 16) & 1u);   // RNE
    return (u16)(u >> 16);
}
__device__ __forceinline__ void load8(const u16* p, float* v) {
    uint4 u = *(const uint4*)p;
    v[0] = bf2f(u.x & 0xffffu); v[1] = bf2f(u.x >> 16);
    v[2] = bf2f(u.y & 0xffffu); v[3] = bf2f(u.y >> 16);
    v[4] = bf2f(u.z & 0xffffu); v[5] = bf2f(u.z >> 16);
    v[6] = bf2f(u.w & 0xffffu); v[7] = bf2f(u.w >> 16);
}
__device__ __forceinline__ uint4 pack8(const float* v) {
    uint4 u;
    u.x = (unsigned)f2bf(v[0]) | ((unsigned)f2bf(v[1]) << 16);
    u.y = (unsigned)f2bf(v[2]) | ((unsigned)f2bf(v[3]) << 16);
    u.z = (unsigned)f2bf(v[4]) | ((unsigned)f2bf(v[5]) << 16);
    u.w = (unsigned)f2bf(v[6]) | ((unsigned)f2bf(v[7]) << 16);
    return u;
}
__device__ __forceinline__ void async16(const u16* g, u16* lds) {
    __builtin_amdgcn_global_load_lds(
        (const __attribute__((address_space(1))) unsigned int*)g,
        (__attribute__((address_space(3))) unsigned int*)lds, 16, 0, 0);
}

#define FENCE() asm volatile("" ::: "memory")
#define BARRIER() do { FENCE(); __builtin_amdgcn_s_barrier(); FENCE(); } while (0)
#define WAITV(n) asm volatile("s_waitcnt vmcnt(" #n ")" ::: "memory")
#define LGKM0()  asm volatile("s_waitcnt lgkmcnt(0)" ::: "memory")

// ==== prep: foldq | wconv | wmix1 | ctxbf | subuf zero ===================
__device__ void prep_body(unsigned bid, int tid,
                          const float* __restrict__ in_proj_w,
                          const float* __restrict__ in_proj_b,
                          const float* __restrict__ qb,
                          const float* __restrict__ concat_w,
                          const float* __restrict__ mix_w1,
                          const float* __restrict__ mix_w2,
                          const float* __restrict__ context,
                          float* __restrict__ bqp,
                          u16* __restrict__ cwbf, u16* __restrict__ m1bf,
                          u16* __restrict__ m2bf, u16* __restrict__ ctxbf,
                          float* __restrict__ subuf) {
    if (bid < 128) {
        const int wave = tid >> 6, lane = tid & 63;
        const int j = bid * 4 + wave;
        const int i = lane * 8;
        float4 w0 = *(const float4*)(in_proj_w + (size_t)j * 512 + i);
        float4 w1 = *(const float4*)(in_proj_w + (size_t)j * 512 + i + 4);
        float4 b0 = *(const float4*)(qb + i);
        float4 b1 = *(const float4*)(qb + i + 4);
        float p1 = w0.x*b0.x + w0.y*b0.y + w0.z*b0.z + w0.w*b0.w
                 + w1.x*b1.x + w1.y*b1.y + w1.z*b1.z + w1.w*b1.w;
        for (int m = 1; m < 64; m <<= 1) p1 += __shfl_xor(p1, m, 64);
        if (lane == 0) bqp[j] = in_proj_b[j] + p1;
    } else if (bid < 320) {
        int i = (bid - 128) * 256 + tid;           // < 49152
        const float* s = concat_w + (size_t)i * 8;
        float4 a = *(const float4*)s;
        float4 b = *(const float4*)(s + 4);
        float v[8] = {a.x, a.y, a.z, a.w, b.x, b.y, b.z, b.w};
        *(uint4*)(cwbf + (size_t)i * 8) = pack8(v);
    } else if (bid < 576) {
        int i = (bid - 320) * 256 + tid;           // < 65536
        const float* s = mix_w2 + (size_t)i * 8;
        float4 a = *(const float4*)s;
        float4 b = *(const float4*)(s + 4);
        float v[8] = {a.x, a.y, a.z, a.w, b.x, b.y, b.z, b.w};
        *(uint4*)(m2bf + (size_t)i * 8) = pack8(v);
    } else if (bid < 1344) {
        int idx = (bid - 576) * 256 + tid;         // < 196608
        int n = idx / 192;
        int k = (idx - n * 192) * 8;
        const float* base = mix_w1 + (size_t)n * 2048;
        float v[8];
        if (k < 512) {
            #pragma unroll
            for (int e = 0; e < 8; e++) v[e] = base[k + e] + base[1024 + k + e];
        } else if (k < 1024) {
            #pragma unroll
            for (int e = 0; e < 8; e++) v[e] = base[k + e] - base[512 + k + e];
        } else {
            #pragma unroll
            for (int e = 0; e < 8; e++) v[e] = base[512 + k + e];
        }
        *(uint4*)(m1bf + (size_t)n * 1536 + k) = pack8(v);
    } else {
        for (int i = tid; i < 2048; i += 256)
            ctxbf[i] = f2bf(context[i]);
        if (tid < 32) subuf[tid] = 0.f;
    }
}

__device__ void ctx_a_body(unsigned task, int tid,
                           const float* __restrict__ context,
                           const float* __restrict__ film_w, const float* __restrict__ film_b,
                           const float* __restrict__ gate_w, const float* __restrict__ gate_b,
                           const float* __restrict__ ctx_w1, const float* __restrict__ ctx_b1,
                           float* __restrict__ gb1, float* __restrict__ betab,
                           float* __restrict__ gateb, float* __restrict__ hbuf) {
    const int wave = tid >> 6, lane = tid & 63;
    const int widx = (int)task * 4 + wave;        // 0..16383
    const int b   = widx >> 11;
    const int j2  = widx & 2047;
    const int cat = j2 >> 9;
    const int j   = j2 & 511;
    const float* wrow;
    if      (cat == 0) wrow = film_w + (size_t)j * 256;
    else if (cat == 1) wrow = film_w + (size_t)(512 + j) * 256;
    else if (cat == 2) wrow = gate_w + (size_t)j * 256;
    else               wrow = ctx_w1 + (size_t)j * 256;
    float4 wv = *(const float4*)(wrow + lane * 4);
    float4 cv = *(const float4*)(context + b * 256 + lane * 4);
    float s = wv.x * cv.x + wv.y * cv.y + wv.z * cv.z + wv.w * cv.w;
    for (int m = 1; m < 64; m <<= 1) s += __shfl_xor(s, m, 64);
    if (lane == 0) {
        if      (cat == 0) gb1[b * 512 + j]   = 1.0f + s + film_b[j];
        else if (cat == 1) betab[b * 512 + j] = s + film_b[512 + j];
        else if (cat == 2) gateb[b * 512 + j] = 1.f / (1.f + expf(-(s + gate_b[j])));
        else {
            float hv = s + ctx_b1[j];
            hbuf[b * 512 + j] = 0.5f * hv * (1.0f + erff(hv * 0.70710678118654752f));
        }
    }
}

// merged prep + ctx_a (independent work, pure grid concatenation)
__global__ void prep_ctxa_kernel(const float* __restrict__ in_proj_w,
                                 const float* __restrict__ in_proj_b,
                                 const float* __restrict__ qb,
                                 const float* __restrict__ concat_w,
                                 const float* __restrict__ mix_w1,
                                 const float* __restrict__ mix_w2,
                                 const float* __restrict__ context,
                                 float* __restrict__ bqp,
                                 u16* __restrict__ cwbf, u16* __restrict__ m1bf,
                                 u16* __restrict__ m2bf, u16* __restrict__ ctxbf,
                                 float* __restrict__ subuf,
                                 const float* __restrict__ film_w, const float* __restrict__ film_b,
                                 const float* __restrict__ gate_w, const float* __restrict__ gate_b,
                                 const float* __restrict__ ctx_w1, const float* __restrict__ ctx_b1,
                                 float* __restrict__ gb1, float* __restrict__ betab,
                                 float* __restrict__ gateb, float* __restrict__ hbuf) {
    if (blockIdx.x < 1345)
        prep_body(blockIdx.x, threadIdx.x, in_proj_w, in_proj_b, qb, concat_w,
                  mix_w1, mix_w2, context, bqp, cwbf, m1bf, m2bf, ctxbf, subuf);
    else
        ctx_a_body(blockIdx.x - 1345, threadIdx.x, context, film_w, film_b,
                   gate_w, gate_b, ctx_w1, ctx_b1, gb1, betab, gateb, hbuf);
}

// ==== context stage B ====================================================
__global__ void ctx_stage_b(const float* __restrict__ hbuf,
                            const float* __restrict__ ctx_w2, const float* __restrict__ ctx_b2,
                            float* __restrict__ tokbuf) {
    const int wave = threadIdx.x >> 6, lane = threadIdx.x & 63;
    const int widx = blockIdx.x * 4 + wave;       // 0..8191
    const int b = widx >> 10;
    const int j = widx & 1023;
    const float* wrow = ctx_w2 + (size_t)j * 512 + lane * 8;
    const float* hr   = hbuf + b * 512 + lane * 8;
    float4 w0 = *(const float4*)wrow, w1 = *(const float4*)(wrow + 4);
    float4 h0 = *(const float4*)hr,   h1 = *(const float4*)(hr + 4);
    float s = w0.x*h0.x + w0.y*h0.y + w0.z*h0.z + w0.w*h0.w
            + w1.x*h1.x + w1.y*h1.y + w1.z*h1.z + w1.w*h1.w;
    for (int m = 1; m < 64; m <<= 1) s += __shfl_xor(s, m, 64);
    if (lane == 0) tokbuf[b * 1024 + j] = s + ctx_b2[j];
}

// ==== context stage C ====================================================
__global__ void ctx_stage_c(const float* __restrict__ tokbuf,
                            const float* __restrict__ in_proj_w, const float* __restrict__ in_proj_b,
                            float* __restrict__ kbuf, float* __restrict__ vbuf) {
    const int wave = threadIdx.x >> 6, lane = threadIdx.x & 63;
    const int widx = blockIdx.x * 4 + wave;       // 0..16383
    const int b  = widx >> 11;
    const int r  = widx & 2047;
    const int t  = r >> 10;
    const int kv = (r >> 9) & 1;
    const int j  = r & 511;
    const float* wrow = in_proj_w + (size_t)(512 + kv * 512 + j) * 512 + lane * 8;
    const float* tk   = tokbuf + (b * 2 + t) * 512 + lane * 8;
    float4 w0 = *(const float4*)wrow, w1 = *(const float4*)(wrow + 4);
    float4 t0 = *(const float4*)tk,   t1 = *(const float4*)(tk + 4);
    float s = w0.x*t0.x + w0.y*t0.y + w0.z*t0.z + w0.w*t0.w
            + w1.x*t1.x + w1.y*t1.y + w1.z*t1.z + w1.w*t1.w;
    for (int m = 1; m < 64; m <<= 1) s += __shfl_xor(s, m, 64);
    if (lane == 0) {
        float v = s + in_proj_b[512 + kv * 512 + j];
        if (kv == 0) kbuf[(b * 2 + t) * 512 + j] = v;
        else         vbuf[(b * 2 + t) * 512 + j] = v;
    }
}

// ==== context stage D, widened: 128 blocks (j-range split) ==============
// bid<64: u/su/c0 (task=bid>>1, jh=bid&1); bid>=64: vo likewise.
__global__ void ctx_stage_d2(const float* __restrict__ in_proj_w,
                             const float* __restrict__ out_proj_w,
                             const float* __restrict__ qg, const float* __restrict__ bqp,
                             const float* __restrict__ kbuf, const float* __restrict__ vbuf,
                             float* __restrict__ ubuf, float* __restrict__ vobuf,
                             float* __restrict__ subuf, float* __restrict__ c0buf) {
    const int tid = threadIdx.x;
    __shared__ float sh[256];
    __shared__ float red[256];
    if (blockIdx.x < 64) {
        const int task = blockIdx.x >> 1, jh = blockIdx.x & 1;
        const int b = task >> 2, idx = task & 3;
        const int t = idx >> 1, h = idx & 1;
        const int j = jh * 256 + tid;
        sh[tid] = kbuf[(b * 2 + t) * 512 + h * 256 + tid];
        __syncthreads();
        float a = 0.f;
        #pragma unroll 4
        for (int dd = 0; dd < 256; dd++)
            a += sh[dd] * in_proj_w[(size_t)(h * 256 + dd) * 512 + j];
        float u = a * qg[j];
        ubuf[task * 512 + j] = u;
        red[tid] = u;
        __syncthreads();
        for (int s = 128; s > 0; s >>= 1) { if (tid < s) red[tid] += red[tid + s]; __syncthreads(); }
        if (tid == 0) atomicAdd(&subuf[task], red[0]);
        if (jh == 0) {          // block-uniform branch
            __syncthreads();
            red[tid] = bqp[h * 256 + tid] * sh[tid];
            __syncthreads();
            for (int s = 128; s > 0; s >>= 1) { if (tid < s) red[tid] += red[tid + s]; __syncthreads(); }
            if (tid == 0) c0buf[task] = red[0];
        }
    } else {
        const int r = blockIdx.x - 64;
        const int task = r >> 1, jh = r & 1;
        const int b = task >> 2, idx = task & 3;
        const int t = idx >> 1, h = idx & 1;
        const int j = jh * 256 + tid;
        sh[tid] = vbuf[(b * 2 + t) * 512 + h * 256 + tid];
        __syncthreads();
        const float* w0 = out_proj_w + (size_t)j * 512 + h * 256;
        float acc0 = 0.f;
        #pragma unroll 2
        for (int dd = 0; dd < 256; dd += 4) {
            float4 x0 = *(const float4*)(w0 + dd);
            acc0 += x0.x*sh[dd] + x0.y*sh[dd+1] + x0.z*sh[dd+2] + x0.w*sh[dd+3];
        }
        vobuf[task * 512 + j] = acc0;
    }
}

// ==== fused stats + attn, 2 rows per wave ================================
// writes xbf->mixA[:,0:512], ao->mixA[:,512:1024], x*ao->pbuf (local rows)
__global__ void statsattn_kernel(const float* __restrict__ x, float* __restrict__ stats,
                                 u16* __restrict__ mixA, u16* __restrict__ pbufH,
                                 const float* __restrict__ ubuf, const float* __restrict__ subuf,
                                 const float* __restrict__ c0buf, const float* __restrict__ vobuf,
                                 const float* __restrict__ ob, const int rowbase) {
    const int wave = threadIdx.x >> 6, lane = threadIdx.x & 63;
    const size_t lr = (size_t)blockIdx.x * 8 + wave * 2;   // local rows lr, lr+1
    const size_t gr = lr + rowbase;
    const int b = (int)(gr >> 12);                          // same for both rows
    float v[2][8], s[2] = {0.f, 0.f}, ss[2] = {0.f, 0.f};
    #pragma unroll
    for (int r = 0; r < 2; r++) {
        const float* xr = x + (gr + r) * 512 + lane * 8;
        float4 a = *(const float4*)xr;
        float4 c = *(const float4*)(xr + 4);
        v[r][0]=a.x; v[r][1]=a.y; v[r][2]=a.z; v[r][3]=a.w;
        v[r][4]=c.x; v[r][5]=c.y; v[r][6]=c.z; v[r][7]=c.w;
        #pragma unroll
        for (int e = 0; e < 8; e++) { s[r] += v[r][e]; ss[r] += v[r][e] * v[r][e]; }
    }
    float u[4][8];
    #pragma unroll
    for (int idx = 0; idx < 4; idx++) {
        const float* up = ubuf + (b * 4 + idx) * 512 + lane * 8;
        float4 u0 = *(const float4*)up, u1 = *(const float4*)(up + 4);
        u[idx][0]=u0.x; u[idx][1]=u0.y; u[idx][2]=u0.z; u[idx][3]=u0.w;
        u[idx][4]=u1.x; u[idx][5]=u1.y; u[idx][6]=u1.z; u[idx][7]=u1.w;
    }
    float sd[2][4];
    #pragma unroll
    for (int r = 0; r < 2; r++)
        #pragma unroll
        for (int idx = 0; idx < 4; idx++) {
            float acc = 0.f;
            #pragma unroll
            for (int e = 0; e < 8; e++) acc += v[r][e] * u[idx][e];
            sd[r][idx] = acc;
        }
    for (int m = 1; m < 64; m <<= 1) {
        #pragma unroll
        for (int r = 0; r < 2; r++) {
            s[r] += __shfl_xor(s[r], m, 64); ss[r] += __shfl_xor(ss[r], m, 64);
            #pragma unroll
            for (int idx = 0; idx < 4; idx++) sd[r][idx] += __shfl_xor(sd[r][idx], m, 64);
        }
    }
    float vo[4][8];
    #pragma unroll
    for (int idx = 0; idx < 4; idx++) {
        const float* vp = vobuf + (b * 4 + idx) * 512 + lane * 8;
        float4 v0 = *(const float4*)vp, v1 = *(const float4*)(vp + 4);
        vo[idx][0]=v0.x; vo[idx][1]=v0.y; vo[idx][2]=v0.z; vo[idx][3]=v0.w;
        vo[idx][4]=v1.x; vo[idx][5]=v1.y; vo[idx][6]=v1.z; vo[idx][7]=v1.w;
    }
    float obp[8];
    {
        const float* op = ob + lane * 8;
        float4 o0 = *(const float4*)op, o1 = *(const float4*)(op + 4);
        obp[0]=o0.x; obp[1]=o0.y; obp[2]=o0.z; obp[3]=o0.w;
        obp[4]=o1.x; obp[5]=o1.y; obp[6]=o1.z; obp[7]=o1.w;
    }
    #pragma unroll
    for (int r = 0; r < 2; r++) {
        const float mean = s[r] * (1.f / 512.f);
        const float rstd = rsqrtf(ss[r] * (1.f / 512.f) - mean * mean + 1e-5f);
        if (lane == 0) { stats[(gr + r) * 2] = mean; stats[(gr + r) * 2 + 1] = rstd; }
        float sc[4];
        #pragma unroll
        for (int idx = 0; idx < 4; idx++)
            sc[idx] = (rstd * (sd[r][idx] - mean * subuf[b * 4 + idx]) + c0buf[b * 4 + idx]) * (1.f / 16.f);
        float p[4];
        #pragma unroll
        for (int h = 0; h < 2; h++) {
            float s0 = sc[h], s1 = sc[2 + h];
            float mx = fmaxf(s0, s1);
            float e0 = expf(s0 - mx), e1 = expf(s1 - mx);
            float inv = 1.f / (e0 + e1);
            p[h] = e0 * inv; p[2 + h] = e1 * inv;
        }
        float o[8], pr[8];
        #pragma unroll
        for (int e = 0; e < 8; e++) {
            o[e] = p[0]*vo[0][e] + p[1]*vo[1][e] + p[2]*vo[2][e] + p[3]*vo[3][e] + obp[e];
            pr[e] = v[r][e] * o[e];
        }
        *(uint4*)(mixA + (gr + r) * 1024 + lane * 8)       = pack8(v[r]);
        *(uint4*)(mixA + (gr + r) * 1024 + 512 + lane * 8) = pack8(o);
        *(uint4*)(pbufH + (lr + r) * 512 + lane * 8)       = pack8(pr);
    }
}

// ==== 256x256 8-phase counted-vmcnt GEMM body (R2-proven schedule) =======
// AMODE 0: A = A0 (ld 1024)                          [mix2, NT=16]
// AMODE 1: A = [A0(ld1024, kt<8) | A1 ctx broadcast] [concat, NT=12]
// AMODE 2: A = [A0(ld1024, kt<16) | A1(ld512)]       [mix1, NT=24]
template<int AMODE, int NT, bool RELU>
__device__ __forceinline__ void gemm8_body(const u16* __restrict__ A0, const u16* __restrict__ A1,
                                           const u16* __restrict__ Wb, const float* __restrict__ bias,
                                           u16* __restrict__ out, const int ldo,
                                           const int bx, const int by, u16* S) {
    constexpr int BLD = NT * 64;                 // B leading dim = K
    constexpr int NIT = NT / 2;
    u16* As = S;
    u16* Bs = S + 32768;
    const int tid = threadIdx.x;
    const int l = tid & 63;
    const int w = tid >> 6;
    const int wm = w >> 2, wn = w & 3;
    const int quad = l >> 4, lc = l & 15;
    const size_t m0 = (size_t)bx * 256;
    const int n0 = by * 256;
    const int bidx = (int)(m0 >> 12);

    // staging: slot s = tid (+512); row r = s>>3, swizzled chunk (s&7)^(r&7)
    const int r0 = tid >> 3;
    const int r1 = (tid + 512) >> 3;
    const int c0s = ((tid & 7) ^ (r0 & 7)) * 8;
    const int c1s = ((tid & 7) ^ (r1 & 7)) * 8;

    auto stA = [&](int kt, int h, int buf) {
        u16* dst = As + (buf * 2 + h) * 8192;
        if constexpr (AMODE == 0) {
            async16(A0 + (m0 + h * 128 + r0) * 1024 + kt * 64 + c0s, dst + tid * 8);
            async16(A0 + (m0 + h * 128 + r1) * 1024 + kt * 64 + c1s, dst + (tid + 512) * 8);
        } else if constexpr (AMODE == 1) {
            if (kt < 8) {
                async16(A0 + (m0 + h * 128 + r0) * 1024 + kt * 64 + c0s, dst + tid * 8);
                async16(A0 + (m0 + h * 128 + r1) * 1024 + kt * 64 + c1s, dst + (tid + 512) * 8);
            } else {
                async16(A1 + bidx * 256 + (kt - 8) * 64 + c0s, dst + tid * 8);
                async16(A1 + bidx * 256 + (kt - 8) * 64 + c1s, dst + (tid + 512) * 8);
            }
        } else {
            if (kt < 16) {
                async16(A0 + (m0 + h * 128 + r0) * 1024 + kt * 64 + c0s, dst + tid * 8);
                async16(A0 + (m0 + h * 128 + r1) * 1024 + kt * 64 + c1s, dst + (tid + 512) * 8);
            } else {
                async16(A1 + (m0 + h * 128 + r0) * 512 + (kt - 16) * 64 + c0s, dst + tid * 8);
                async16(A1 + (m0 + h * 128 + r1) * 512 + (kt - 16) * 64 + c1s, dst + (tid + 512) * 8);
            }
        }
    };
    auto stB = [&](int kt, int h, int buf) {
        u16* dst = Bs + (buf * 2 + h) * 8192;
        async16(Wb + (size_t)(n0 + h * 128 + r0) * BLD + kt * 64 + c0s, dst + tid * 8);
        async16(Wb + (size_t)(n0 + h * 128 + r1) * BLD + kt * 64 + c1s, dst + (tid + 512) * 8);
    };

    bf16x8 a_[4][2], b_[2][2][2];
    f32x4 acc[8][4];
    #pragma unroll
    for (int i = 0; i < 8; i++)
        #pragma unroll
        for (int j = 0; j < 4; j++) acc[i][j] = (f32x4){0.f, 0.f, 0.f, 0.f};

    auto rdA = [&](int buf, int qi) {
        const u16* Ab = As + (buf * 2 + wm) * 8192;
        #pragma unroll
        for (int ii = 0; ii < 4; ii++) {
            const int r = (qi * 4 + ii) * 16 + lc;
            #pragma unroll
            for (int kk = 0; kk < 2; kk++) {
                const int cs = (kk * 4 + quad) ^ (r & 7);
                a_[ii][kk] = *(const bf16x8*)&Ab[r * 64 + cs * 8];
            }
        }
    };
    auto rdB = [&](int buf, int qj) {
        #pragma unroll
        for (int jj = 0; jj < 2; jj++) {
            const int nr = wn * 64 + (qj * 2 + jj) * 16 + lc;
            const int hb = nr >> 7, r = nr & 127;
            const u16* Bb = Bs + (buf * 2 + hb) * 8192;
            #pragma unroll
            for (int kk = 0; kk < 2; kk++) {
                const int cs = (kk * 4 + quad) ^ (r & 7);
                b_[qj][jj][kk] = *(const bf16x8*)&Bb[r * 64 + cs * 8];
            }
        }
    };
    auto mfma16 = [&](int qi, int qj) {
        __builtin_amdgcn_s_setprio(1);
        #pragma unroll
        for (int ii = 0; ii < 4; ii++)
            #pragma unroll
            for (int jj = 0; jj < 2; jj++)
                #pragma unroll
                for (int kk = 0; kk < 2; kk++)
                    acc[qi * 4 + ii][qj * 2 + jj] = __builtin_amdgcn_mfma_f32_16x16x32_bf16(
                        a_[ii][kk], b_[qj][jj][kk], acc[qi * 4 + ii][qj * 2 + jj], 0, 0, 0);
        __builtin_amdgcn_s_setprio(0);
    };

    // prologue: K-tile 0 -> buf0 (4 half-tiles), K-tile 1 A-h0 -> buf1
    stA(0, 0, 0); stA(0, 1, 0); stB(0, 0, 0); stB(0, 1, 0);
    stA(1, 0, 1);
    WAITV(2); BARRIER();

    for (int it = 0; it < NIT; it++) {
        const int tb = 2 * it + 1;               // odd K-tile of this iter
        const bool more = (it < NIT - 1);
        // -- K-tile 2*it from buf0 --
        // ph1
        rdA(0, 0); rdB(0, 0);
        stA(tb, 1, 1);
        BARRIER(); mfma16(0, 0);
        // ph2
        rdB(0, 1);
        stB(tb, 0, 1);
        BARRIER(); mfma16(0, 1);
        // ph3
        rdA(0, 1);
        stB(tb, 1, 1);
        BARRIER(); mfma16(1, 1);
        BARRIER();                               // buf0-A reads retired before ph4 stage
        // ph4
        if (more) { stA(tb + 1, 0, 0); WAITV(2); }
        else      { WAITV(0); }
        BARRIER(); mfma16(1, 0);
        // -- K-tile tb from buf1 --
        // ph5
        rdA(1, 0); rdB(1, 0);
        if (more) stA(tb + 1, 1, 0);
        BARRIER(); mfma16(0, 0);
        // ph6
        rdB(1, 1);
        if (more) stB(tb + 1, 0, 0);
        BARRIER(); mfma16(0, 1);
        // ph7
        rdA(1, 1);
        if (more) stB(tb + 1, 1, 0);
        BARRIER(); mfma16(1, 1);
        BARRIER();                               // buf1-A reads retired before ph8 stage
        // ph8
        if (more) { stA(tb + 2, 0, 1); WAITV(2); }
        BARRIER(); mfma16(1, 0);
    }

    // epilogue: bias + optional relu, LDS transpose, coalesced bf16 store
    BARRIER();
    float bv[4];
    #pragma unroll
    for (int j = 0; j < 4; j++) bv[j] = bias[n0 + wn * 64 + j * 16 + lc];
    #pragma unroll
    for (int p = 0; p < 2; p++) {
        if (p) BARRIER();
        if (wm == p) {
            #pragma unroll
            for (int i = 0; i < 8; i++)
                #pragma unroll
                for (int j = 0; j < 4; j++)
                    #pragma unroll
                    for (int reg = 0; reg < 4; reg++) {
                        float vv = acc[i][j][reg] + bv[j];
                        if (RELU) vv = fmaxf(vv, 0.f);
                        S[(i * 16 + quad * 4 + reg) * 264 + wn * 64 + j * 16 + lc] = f2bf(vv);
                    }
        }
        LGKM0(); BARRIER();
        #pragma unroll
        for (int kq = 0; kq < 8; kq++) {
            const int cix = tid + kq * 512;      // 0..4095
            const int row = cix >> 5, ch = cix & 31;
            *(uint4*)(out + (m0 + p * 128 + row) * (size_t)ldo + n0 + ch * 8)
                = *(const uint4*)&S[row * 264 + ch * 8];
        }
    }
}

template<int AMODE, int NT, bool RELU>
__launch_bounds__(512, 2)
__global__ void mix_gemm8(const u16* __restrict__ A0, const u16* __restrict__ A1,
                          const u16* __restrict__ Wb, const float* __restrict__ bias,
                          u16* __restrict__ out, const int ldo) {
    extern __shared__ __align__(16) u16 S[];     // 128 KiB
    gemm8_body<AMODE, NT, RELU>(A0, A1, Wb, bias, out, ldo, blockIdx.x, blockIdx.y, S);
}

// mix2 (blocks 0..127) + concat (blocks 128..255) in one dispatch — the two
// GEMMs are independent (mix2: bufh -> mixA[:,512:]; concat: mixA[:,0:512] -> pbuf)
__launch_bounds__(512, 2)
__global__ void mix2_concat_kernel(const u16* __restrict__ bufh, const u16* __restrict__ m2bf,
                                   const float* __restrict__ mix_b2, u16* __restrict__ out_a,
                                   const u16* __restrict__ mixA, const u16* __restrict__ ctxbf,
                                   const u16* __restrict__ cwbf, const float* __restrict__ concat_b,
                                   u16* __restrict__ bufc) {
    extern __shared__ __align__(16) u16 S[];     // 128 KiB
    if (blockIdx.x < 128)
        gemm8_body<0, 16, false>(bufh, nullptr, m2bf, mix_b2, out_a, 1024,
                                 blockIdx.x, blockIdx.y, S);
    else
        gemm8_body<1, 12, true>(mixA, ctxbf, cwbf, concat_b, bufc, 512,
                                blockIdx.x - 128, blockIdx.y, S);
}

// ==== final: upd_c = LN(bufc); LN(base + gate*mask*(upd_c+upd_a)) ========
__global__ void final_kernel(const u16* __restrict__ mixA, const float* __restrict__ stats,
                             const u16* __restrict__ bufc,
                             const float* __restrict__ cg_, const float* __restrict__ cb,
                             const float* __restrict__ gb1, const float* __restrict__ betab,
                             const float* __restrict__ gateb, const int* __restrict__ mask,
                             const float* __restrict__ fg, const float* __restrict__ fb,
                             const float* __restrict__ og, const float* __restrict__ ob,
                             float* __restrict__ out) {
    const int wave = threadIdx.x >> 6, lane = threadIdx.x & 63;
    const size_t row = (size_t)blockIdx.x * 4 + wave;
    const int b = (int)(row >> 12);
    const int c0 = lane * 8;
    float xv[8], uc[8], ua[8];
    load8(mixA + row * 1024 + c0, xv);          // xbf
    load8(mixA + row * 1024 + 512 + c0, ua);    // upd_a
    load8(bufc + row * 512 + c0, uc);           // relu'd concat out (pre-LN)
    float sc = 0.f, ssc = 0.f;
    #pragma unroll
    for (int e = 0; e < 8; e++) { sc += uc[e]; ssc += uc[e] * uc[e]; }
    for (int m = 1; m < 64; m <<= 1) { sc += __shfl_xor(sc, m, 64); ssc += __shfl_xor(ssc, m, 64); }
    const float mc = sc * (1.f / 512.f);
    const float rc = rsqrtf(ssc * (1.f / 512.f) - mc * mc + 1e-5f);
    const float mean = stats[row * 2], rstd = stats[row * 2 + 1];
    const float mf = (mask[row] != 0) ? 1.f : 0.f;
    float y[8];
    float s = 0.f, ss = 0.f;
    #pragma unroll
    for (int e = 0; e < 8; e++) {
        int c = c0 + e;
        float ucn = (uc[e] - mc) * rc * cg_[c] + cb[c];
        float xh = (xv[e] - mean) * rstd;
        float base = gb1[b * 512 + c] * (xh * fg[c] + fb[c]) + betab[b * 512 + c];
        float yv = base + gateb[b * 512 + c] * mf * (ucn + ua[e]);
        y[e] = yv; s += yv; ss += yv * yv;
    }
    for (int m = 1; m < 64; m <<= 1) { s += __shfl_xor(s, m, 64); ss += __shfl_xor(ss, m, 64); }
    float mean2 = s * (1.f / 512.f);
    float rstd2 = rsqrtf(ss * (1.f / 512.f) - mean2 * mean2 + 1e-5f);
    float o[8];
    #pragma unroll
    for (int e = 0; e < 8; e++) {
        int c = c0 + e;
        o[e] = (y[e] - mean2) * rstd2 * og[c] + ob[c];
    }
    *(float4*)(out + row * 512 + c0)     = make_float4(o[0], o[1], o[2], o[3]);
    *(float4*)(out + row * 512 + c0 + 4) = make_float4(o[4], o[5], o[6], o[7]);
}

extern "C" void kernel_launch(void* const* d_in, const int* in_sizes, int n_in,
                              void* d_out, int out_size, void* d_ws, size_t ws_size,
                              hipStream_t stream) {
    const float* x          = (const float*)d_in[0];
    const float* context    = (const float*)d_in[1];
    const int*   mask       = (const int*)d_in[2];
    const float* film_ln_g  = (const float*)d_in[3];
    const float* film_ln_b  = (const float*)d_in[4];
    const float* film_w     = (const float*)d_in[5];
    const float* film_b     = (const float*)d_in[6];
    const float* concat_w   = (const float*)d_in[7];
    const float* concat_b   = (const float*)d_in[8];
    const float* concat_ln_g= (const float*)d_in[9];
    const float* concat_ln_b= (const float*)d_in[10];
    const float* ctx_w1     = (const float*)d_in[11];
    const float* ctx_b1     = (const float*)d_in[12];
    const float* ctx_w2     = (const float*)d_in[13];
    const float* ctx_b2     = (const float*)d_in[14];
    const float* q_ln_g     = (const float*)d_in[15];
    const float* q_ln_b     = (const float*)d_in[16];
    const float* in_proj_w  = (const float*)d_in[17];
    const float* in_proj_b  = (const float*)d_in[18];
    const float* out_proj_w = (const float*)d_in[19];
    const float* out_proj_b = (const float*)d_in[20];
    const float* mix_w1     = (const float*)d_in[21];
    const float* mix_b1     = (const float*)d_in[22];
    const float* mix_w2     = (const float*)d_in[23];
    const float* mix_b2     = (const float*)d_in[24];
    const float* out_ln_g   = (const float*)d_in[25];
    const float* out_ln_b   = (const float*)d_in[26];
    const float* gate_w     = (const float*)d_in[27];
    const float* gate_b     = (const float*)d_in[28];
    float* out = (float*)d_out;

    // ---- workspace layout ----
    float* gb1    = (float*)d_ws;            // 4096
    float* betab  = gb1 + 4096;
    float* gateb  = betab + 4096;
    float* kbuf   = gateb + 4096;            // 8192
    float* vbuf   = kbuf + 8192;
    float* bqp    = vbuf + 8192;             // 512
    float* hbuf   = bqp + 512;               // 4096
    float* tokbuf = hbuf + 4096;             // 8192
    float* ubuf   = tokbuf + 8192;           // 16384
    float* vobuf  = ubuf + 16384;            // 16384
    float* subuf  = vobuf + 16384;           // 32
    float* c0buf  = subuf + 32;              // 32
    float* stats  = c0buf + 32;              // 65536
    u16* ctxbf = (u16*)(stats + 65536);      // 2048
    u16* cwbf  = ctxbf + 2048;               // 393216
    u16* m1bf  = cwbf + 393216;              // 1572864
    u16* m2bf  = m1bf + 1572864;             // 524288
    u16* mixA  = m2bf + 524288;                        // 32768*1024 [xbf | ao->upd_a]
    u16* bufh  = mixA + (size_t)N_TOK * 1024;          // 32768*1024 full h
    u16* pbuf  = bufh + (size_t)N_TOK * 1024;          // x*ao: full (32MB) or half (16MB)

    // full path needs 173,316,352 B; half path 156,539,136 B
    const bool full = (ws_size >= 173316352ull);

    static bool attr_set = false;
    if (!attr_set) {
        hipFuncSetAttribute(reinterpret_cast<const void*>(&mix_gemm8<2, 24, true>),
                            hipFuncAttributeMaxDynamicSharedMemorySize, 131072);
        hipFuncSetAttribute(reinterpret_cast<const void*>(&mix_gemm8<0, 16, false>),
                            hipFuncAttributeMaxDynamicSharedMemorySize, 131072);
        hipFuncSetAttribute(reinterpret_cast<const void*>(&mix_gemm8<1, 12, true>),
                            hipFuncAttributeMaxDynamicSharedMemorySize, 131072);
        hipFuncSetAttribute(reinterpret_cast<const void*>(&mix2_concat_kernel),
                            hipFuncAttributeMaxDynamicSharedMemorySize, 131072);
        attr_set = true;
    }

    prep_ctxa_kernel<<<5441, 256, 0, stream>>>(
        in_proj_w, in_proj_b, q_ln_b, concat_w, mix_w1, mix_w2, context,
        bqp, cwbf, m1bf, m2bf, ctxbf, subuf,
        film_w, film_b, gate_w, gate_b, ctx_w1, ctx_b1,
        gb1, betab, gateb, hbuf);
    ctx_stage_b<<<2048, 256, 0, stream>>>(hbuf, ctx_w2, ctx_b2, tokbuf);
    ctx_stage_c<<<4096, 256, 0, stream>>>(tokbuf, in_proj_w, in_proj_b, kbuf, vbuf);
    ctx_stage_d2<<<128, 256, 0, stream>>>(in_proj_w, out_proj_w, q_ln_g, bqp,
                                          kbuf, vbuf, ubuf, vobuf, subuf, c0buf);

    if (full) {
        u16* bufc = pbuf;                    // concat out aliases pbuf (dead after mix1)
        statsattn_kernel<<<N_TOK / 8, 256, 0, stream>>>(
            x, stats, mixA, pbuf, ubuf, subuf, c0buf, vobuf, out_proj_b, 0);
        mix_gemm8<2, 24, true><<<dim3(128, 4), 512, 131072, stream>>>(
            mixA, pbuf, m1bf, mix_b1, bufh, 1024);
        mix2_concat_kernel<<<dim3(256, 2), 512, 131072, stream>>>(
            bufh, m2bf, mix_b2, mixA + 512,
            mixA, ctxbf, cwbf, concat_b, bufc);
        final_kernel<<<N_TOK / 4, 256, 0, stream>>>(mixA, stats, bufc,
                                                    concat_ln_g, concat_ln_b,
                                                    gb1, betab, gateb, mask,
                                                    film_ln_g, film_ln_b,
                                                    out_ln_g, out_ln_b, out);
    } else {
        // fallback: R2 half-path (bufc aliases bufh; mix2 before concat)
        u16* bufc = bufh;
        for (int h = 0; h < 2; h++) {
            const int rowbase = h * HALF_ROWS;
            statsattn_kernel<<<HALF_ROWS / 8, 256, 0, stream>>>(
                x, stats, mixA, pbuf, ubuf, subuf, c0buf, vobuf, out_proj_b, rowbase);
            mix_gemm8<2, 24, true><<<dim3(64, 4), 512, 131072, stream>>>(
                mixA + (size_t)rowbase * 1024, pbuf, m1bf, mix_b1,
                bufh + (size_t)rowbase * 1024, 1024);
        }
        mix_gemm8<0, 16, false><<<dim3(128, 2), 512, 131072, stream>>>(
            bufh, nullptr, m2bf, mix_b2, mixA + 512, 1024);
        mix_gemm8<1, 12, true><<<dim3(128, 2), 512, 131072, stream>>>(
            mixA, ctxbf, cwbf, concat_b, bufc, 512);
        final_kernel<<<N_TOK / 4, 256, 0, stream>>>(mixA, stats, bufc,
                                                    concat_ln_g, concat_ln_b,
                                                    gb1, betab, gateb, mask,
                                                    film_ln_g, film_ln_b,
                                                    out_ln_g, out_ln_b, out);
    }
    (void)in_sizes; (void)n_in; (void)out_size; (void)ws_size;
}